// Round 9
// baseline (539.586 us; speedup 1.0000x reference)
//
#include <hip/hip_runtime.h>
#include <hip/hip_bf16.h>

typedef unsigned short u16;
typedef __bf16 bfx8 __attribute__((ext_vector_type(8)));
typedef float fx4 __attribute__((ext_vector_type(4)));

#define SEQ 2048
#define DIM 1024
#define NBATCH 4
#define SCALE 0.03125f  // 1/sqrt(1024)
#define NEL ((size_t)NBATCH * SEQ * DIM)   // 8388608 elems per Q/K/V

__device__ inline u16 f2bf(float f) {
    __bf16 h = (__bf16)f;
    return __builtin_bit_cast(unsigned short, h);
}

// async global->LDS, 16B per lane (dst must be wave-uniform base + lane*16)
#define GLL(gp, lp) __builtin_amdgcn_global_load_lds( \
    (const __attribute__((address_space(1))) unsigned int*)(gp), \
    (__attribute__((address_space(3))) unsigned int*)(lp), 16, 0, 0)

// ---------------------------------------------------------------------------
// prep: fused convert_x (blocks [0,8192)) + convert_w (blocks [8192,11264))
//       + zero Lrow (blocks [11264,11296)).  One dispatch instead of three.
// ---------------------------------------------------------------------------
__global__ __launch_bounds__(256) void prep(
    const float* __restrict__ X,
    const float* __restrict__ Wq, const float* __restrict__ Wk,
    const float* __restrict__ Wv,
    u16* __restrict__ XB, u16* __restrict__ WT, float* __restrict__ Lrow)
{
    __shared__ u16 t[32][33];
    int bid = blockIdx.x;
    int tid = threadIdx.x;
    if (bid < 8192) {
        size_t i = (size_t)bid * 256 + tid;
        float4 v = ((const float4*)X)[i];
        uint2 pk;
        pk.x = (unsigned)f2bf(v.x) | ((unsigned)f2bf(v.y) << 16);
        pk.y = (unsigned)f2bf(v.z) | ((unsigned)f2bf(v.w) << 16);
        ((uint2*)XB)[i] = pk;
    } else if (bid < 11264) {
        int tt = bid - 8192;
        int z = tt >> 10, t2 = tt & 1023;
        const float* W = (z == 0) ? Wq : (z == 1) ? Wk : Wv;
        u16* out = WT + (size_t)z * 1024 * 1024;
        int n0 = (t2 & 31) * 32, k0 = (t2 >> 5) * 32;
        int tx = tid & 31, ty = tid >> 5;
        #pragma unroll
        for (int i = 0; i < 32; i += 8)
            t[ty + i][tx] = f2bf(W[(size_t)(k0 + ty + i) * 1024 + n0 + tx]);
        __syncthreads();
        #pragma unroll
        for (int i = 0; i < 32; i += 8)
            out[(size_t)(n0 + ty + i) * 1024 + k0 + tx] = t[tx][ty + i];
    } else {
        int i = (bid - 11264) * 256 + tid;   // 8192 floats
        Lrow[i] = 0.0f;
    }
}

// ---------------------------------------------------------------------------
// gemm_fast: C = XB[8192,1024] x W (bf16, k-contig both sides).  GLL staging.
// WG tile 128x256.  LDS UNION: the V-transpose staging buffer (33 KB, used
// only after the K-loop) aliases the As/Bs staging region (24 KB) -> total
// LDS 33 KB -> 4 WG/CU (r8's separate Ct gave 58 KB -> 2 WG/CU -> 100 us).
// ---------------------------------------------------------------------------
__global__ __launch_bounds__(256, 4) void gemm_fast(
    const u16* __restrict__ XB, const u16* __restrict__ WT,
    u16* __restrict__ Qo, u16* __restrict__ Ko, u16* __restrict__ VTo)
{
    const u16* Wz = WT + (size_t)blockIdx.z * 1024 * 1024;
    int m0 = blockIdx.y * 128, n0 = blockIdx.x * 256;

    // union: [As: 4096 u16][Bs: 8192 u16] vs [Ct: 64*260 u16]
    __shared__ __align__(16) u16 lds[64 * 260];    // 33280 B
    u16* As = lds;                                  // 128*32
    u16* Bs = lds + 4096;                           // 256*32
    u16* Ct = lds;                                  // 64 rows x 260 stride

    int tid = threadIdx.x, lane = tid & 63, w = tid >> 6;
    int wm = w >> 1, wn = w & 1, lo = lane & 15, qd = lane >> 4;

    fx4 acc[4][8] = {};

    int c0 = tid, c1 = tid + 256;
    const u16* a0 = XB + (size_t)(m0 + (c0 >> 2)) * 1024 + (c0 & 3) * 8;
    const u16* a1 = XB + (size_t)(m0 + (c1 >> 2)) * 1024 + (c1 & 3) * 8;
    const u16* bp0 = Wz + (size_t)(n0 + (c0 >> 2)) * 1024 + (c0 & 3) * 8;
    const u16* bp1 = Wz + (size_t)(n0 + ((tid + 256) >> 2)) * 1024 + ((tid + 256) & 3) * 8;
    const u16* bp2 = Wz + (size_t)(n0 + ((tid + 512) >> 2)) * 1024 + ((tid + 512) & 3) * 8;
    const u16* bp3 = Wz + (size_t)(n0 + ((tid + 768) >> 2)) * 1024 + ((tid + 768) & 3) * 8;

    for (int k0 = 0; k0 < 1024; k0 += 32) {
        GLL(a0 + k0, &As[(size_t)c0 * 8]);
        GLL(a1 + k0, &As[(size_t)c1 * 8]);
        GLL(bp0 + k0, &Bs[(size_t)tid * 8]);
        GLL(bp1 + k0, &Bs[(size_t)(tid + 256) * 8]);
        GLL(bp2 + k0, &Bs[(size_t)(tid + 512) * 8]);
        GLL(bp3 + k0, &Bs[(size_t)(tid + 768) * 8]);
        __syncthreads();

        bfx8 af[4];
        #pragma unroll
        for (int i = 0; i < 4; i++)
            af[i] = *(const bfx8*)(&As[(wm * 64 + i * 16 + lo) * 32 + qd * 8]);
        #pragma unroll
        for (int j = 0; j < 8; j++) {
            bfx8 bf = *(const bfx8*)(&Bs[(wn * 128 + j * 16 + lo) * 32 + qd * 8]);
            #pragma unroll
            for (int i = 0; i < 4; i++)
                acc[i][j] = __builtin_amdgcn_mfma_f32_16x16x32_bf16(af[i], bf, acc[i][j], 0, 0, 0);
        }
        __syncthreads();
    }

    if (blockIdx.z != 2) {
        u16* C = (blockIdx.z == 0) ? Qo : Ko;
        #pragma unroll
        for (int i = 0; i < 4; i++)
            #pragma unroll
            for (int j = 0; j < 8; j++)
                #pragma unroll
                for (int r = 0; r < 4; r++) {
                    int row = m0 + wm * 64 + i * 16 + qd * 4 + r;
                    int col = n0 + wn * 128 + j * 16 + lo;
                    C[(size_t)row * 1024 + col] = f2bf(acc[i][j][r]);
                }
    } else {
        // V: store transposed via Ct (aliases staging; safe after final barrier)
        #pragma unroll
        for (int half = 0; half < 2; half++) {
            __syncthreads();
            if (wm == half) {
                #pragma unroll
                for (int i = 0; i < 4; i++)
                    #pragma unroll
                    for (int j = 0; j < 8; j++)
                        #pragma unroll
                        for (int r = 0; r < 4; r++)
                            Ct[(i * 16 + qd * 4 + r) * 260 + wn * 128 + j * 16 + lo]
                                = f2bf(acc[i][j][r]);
            }
            __syncthreads();
            #pragma unroll
            for (int e = tid; e < 64 * 256; e += 256) {
                int d = e >> 6, sl = e & 63;
                int gr = m0 + half * 64 + sl;
                int bb = gr >> 11, s = gr & 2047;
                VTo[((size_t)bb * DIM + (n0 + d)) * SEQ + s] = Ct[sl * 260 + d];
            }
        }
    }
}

// ---------------------------------------------------------------------------
// gemm_legacy: fp32-staging GEMM fallback (small ws).
// ---------------------------------------------------------------------------
__global__ __launch_bounds__(256) void gemm_legacy(
    const float* __restrict__ X,
    const float* __restrict__ Wq, const float* __restrict__ Wk, const float* __restrict__ Wv,
    u16* __restrict__ Qo, u16* __restrict__ Ko, u16* __restrict__ VTo)
{
    const int K = 1024, N = 1024;
    const float* W = (blockIdx.z == 0) ? Wq : (blockIdx.z == 1) ? Wk : Wv;
    int m0 = blockIdx.y * 128, n0 = blockIdx.x * 128;
    __shared__ __align__(16) u16 As[128 * 40];
    __shared__ __align__(16) u16 Bs[128 * 40];
    __shared__ __align__(16) u16 Ct[64][132];
    int tid = threadIdx.x, lane = tid & 63, w = tid >> 6;
    int wm = w >> 1, wn = w & 1, lo = lane & 15, qd = lane >> 4;
    fx4 acc[4][4] = {};
    for (int k0 = 0; k0 < K; k0 += 32) {
        #pragma unroll
        for (int c = tid; c < 1024; c += 256) {
            int row = c >> 3, cc = (c & 7) * 4;
            float4 v = *(const float4*)(X + (size_t)(m0 + row) * K + k0 + cc);
            uint2 pk;
            pk.x = (unsigned)f2bf(v.x) | ((unsigned)f2bf(v.y) << 16);
            pk.y = (unsigned)f2bf(v.z) | ((unsigned)f2bf(v.w) << 16);
            *(uint2*)(&As[row * 40 + cc]) = pk;
        }
        #pragma unroll
        for (int c = tid; c < 1024; c += 256) {
            int r = c >> 5, cc = (c & 31) * 4;
            float4 v = *(const float4*)(W + (size_t)(k0 + r) * N + n0 + cc);
            Bs[(cc + 0) * 40 + r] = f2bf(v.x);
            Bs[(cc + 1) * 40 + r] = f2bf(v.y);
            Bs[(cc + 2) * 40 + r] = f2bf(v.z);
            Bs[(cc + 3) * 40 + r] = f2bf(v.w);
        }
        __syncthreads();
        bfx8 af[4], bf[4];
        #pragma unroll
        for (int i = 0; i < 4; i++)
            af[i] = *(const bfx8*)(&As[(wm * 64 + i * 16 + lo) * 40 + qd * 8]);
        #pragma unroll
        for (int j = 0; j < 4; j++)
            bf[j] = *(const bfx8*)(&Bs[(wn * 64 + j * 16 + lo) * 40 + qd * 8]);
        #pragma unroll
        for (int i = 0; i < 4; i++)
            #pragma unroll
            for (int j = 0; j < 4; j++)
                acc[i][j] = __builtin_amdgcn_mfma_f32_16x16x32_bf16(af[i], bf[j], acc[i][j], 0, 0, 0);
        __syncthreads();
    }
    if (blockIdx.z != 2) {
        u16* C = (blockIdx.z == 0) ? Qo : Ko;
        #pragma unroll
        for (int i = 0; i < 4; i++)
            #pragma unroll
            for (int j = 0; j < 4; j++)
                #pragma unroll
                for (int r = 0; r < 4; r++) {
                    int row = m0 + wm * 64 + i * 16 + qd * 4 + r;
                    int col = n0 + wn * 64 + j * 16 + lo;
                    C[(size_t)row * N + col] = f2bf(acc[i][j][r]);
                }
    } else {
        #pragma unroll
        for (int half = 0; half < 2; half++) {
            __syncthreads();
            if (wm == half) {
                #pragma unroll
                for (int i = 0; i < 4; i++)
                    #pragma unroll
                    for (int j = 0; j < 4; j++)
                        #pragma unroll
                        for (int r = 0; r < 4; r++)
                            Ct[i * 16 + qd * 4 + r][wn * 64 + j * 16 + lo] = f2bf(acc[i][j][r]);
            }
            __syncthreads();
            #pragma unroll
            for (int e = tid; e < 64 * 128; e += 256) {
                int d = e >> 6, sl = e & 63;
                int gr = m0 + half * 64 + sl;
                int bb = gr >> 11, s = gr & 2047;
                VTo[((size_t)bb * DIM + (n0 + d)) * SEQ + s] = Ct[sl][d];
            }
        }
    }
}

// ---------------------------------------------------------------------------
// sgemm_exp: P[q][k] = exp(scale*(Q x K^T) masked), causal 128x128 tiles only,
// bf16 out, UNNORMALIZED (no max-subtraction; scores clamped +-30).
// Row sums accumulated into Lrow via atomicAdd.
// ---------------------------------------------------------------------------
__global__ __launch_bounds__(256) void sgemm_exp(
    const u16* __restrict__ Q, const u16* __restrict__ K,
    u16* __restrict__ P, float* __restrict__ Lrow)
{
    int b = blockIdx.y;
    int t = blockIdx.x;                  // 0..135 triangular tile
    int i = (int)((sqrtf(8.0f * t + 1.0f) - 1.0f) * 0.5f);
    while ((i + 1) * (i + 2) / 2 <= t) i++;
    while (i * (i + 1) / 2 > t) i--;
    int j = t - i * (i + 1) / 2;

    const u16* Qb = Q + (size_t)b * SEQ * DIM;
    const u16* Kb = K + (size_t)b * SEQ * DIM;
    u16* Pb = P + (size_t)b * SEQ * SEQ;
    float* Lb = Lrow + (size_t)b * SEQ;

    int m0 = i * 128, n0 = j * 128;

    __shared__ __align__(16) u16 As[128 * 32];
    __shared__ __align__(16) u16 Bs[128 * 32];

    int tid = threadIdx.x, lane = tid & 63, w = tid >> 6;
    int wm = w >> 1, wn = w & 1, lo = lane & 15, qd = lane >> 4;

    fx4 acc[4][4] = {};

    int c0 = tid, c1 = tid + 256;
    const u16* a0 = Qb + (size_t)(m0 + (c0 >> 2)) * DIM + (c0 & 3) * 8;
    const u16* a1 = Qb + (size_t)(m0 + (c1 >> 2)) * DIM + (c1 & 3) * 8;
    const u16* b0 = Kb + (size_t)(n0 + (c0 >> 2)) * DIM + (c0 & 3) * 8;
    const u16* b1 = Kb + (size_t)(n0 + (c1 >> 2)) * DIM + (c1 & 3) * 8;

    for (int k0 = 0; k0 < 1024; k0 += 32) {
        GLL(a0 + k0, &As[(size_t)c0 * 8]);
        GLL(a1 + k0, &As[(size_t)c1 * 8]);
        GLL(b0 + k0, &Bs[(size_t)c0 * 8]);
        GLL(b1 + k0, &Bs[(size_t)c1 * 8]);
        __syncthreads();

        bfx8 af[4], bf[4];
        #pragma unroll
        for (int ii = 0; ii < 4; ii++)
            af[ii] = *(const bfx8*)(&As[(wm * 64 + ii * 16 + lo) * 32 + qd * 8]);
        #pragma unroll
        for (int jj = 0; jj < 4; jj++)
            bf[jj] = *(const bfx8*)(&Bs[(wn * 64 + jj * 16 + lo) * 32 + qd * 8]);
        #pragma unroll
        for (int ii = 0; ii < 4; ii++)
            #pragma unroll
            for (int jj = 0; jj < 4; jj++)
                acc[ii][jj] = __builtin_amdgcn_mfma_f32_16x16x32_bf16(af[ii], bf[jj], acc[ii][jj], 0, 0, 0);
        __syncthreads();
    }

    #pragma unroll
    for (int ii = 0; ii < 4; ii++)
        #pragma unroll
        for (int r = 0; r < 4; r++) {
            int row = m0 + wm * 64 + ii * 16 + qd * 4 + r;
            float rs = 0.0f;
            #pragma unroll
            for (int jj = 0; jj < 4; jj++) {
                int col = n0 + wn * 64 + jj * 16 + lo;
                float s = acc[ii][jj][r] * SCALE;
                s = fminf(fmaxf(s, -30.0f), 30.0f);
                float p = (col > row) ? 0.0f : __expf(s);
                Pb[(size_t)row * SEQ + col] = f2bf(p);
                rs += p;
            }
            #pragma unroll
            for (int off = 1; off < 16; off <<= 1) rs += __shfl_xor(rs, off);
            if (lo == 0) atomicAdd(&Lb[row], rs);
        }
}

// ---------------------------------------------------------------------------
// pvgemm: O[q][d] = P[q][k] x VT[d][k] / L[q].  Triangular k-extent per
// q-block; biggest q-blocks dispatched first.  Both operands key-contiguous.
// ---------------------------------------------------------------------------
__global__ __launch_bounds__(256) void pvgemm(
    const u16* __restrict__ P, const u16* __restrict__ VT,
    const float* __restrict__ Lrow, float* __restrict__ O)
{
    int b = blockIdx.y;
    int qb = 15 - (int)(blockIdx.x >> 3);   // big k-extent first
    int db = blockIdx.x & 7;
    int m0 = qb * 128, n0 = db * 128;
    int kext = (qb + 1) * 128;

    const u16* Pb = P + (size_t)b * SEQ * SEQ;
    const u16* Vb = VT + (size_t)b * DIM * SEQ;
    const float* Lb = Lrow + (size_t)b * SEQ;
    float* Ob = O + (size_t)b * SEQ * DIM;

    __shared__ __align__(16) u16 As[128 * 32];
    __shared__ __align__(16) u16 Bs[128 * 32];

    int tid = threadIdx.x, lane = tid & 63, w = tid >> 6;
    int wm = w >> 1, wn = w & 1, lo = lane & 15, qd = lane >> 4;

    fx4 acc[4][4] = {};

    int c0 = tid, c1 = tid + 256;
    const u16* a0 = Pb + (size_t)(m0 + (c0 >> 2)) * SEQ + (c0 & 3) * 8;
    const u16* a1 = Pb + (size_t)(m0 + (c1 >> 2)) * SEQ + (c1 & 3) * 8;
    const u16* b0 = Vb + (size_t)(n0 + (c0 >> 2)) * SEQ + (c0 & 3) * 8;
    const u16* b1 = Vb + (size_t)(n0 + (c1 >> 2)) * SEQ + (c1 & 3) * 8;

    for (int k0 = 0; k0 < kext; k0 += 32) {
        GLL(a0 + k0, &As[(size_t)c0 * 8]);
        GLL(a1 + k0, &As[(size_t)c1 * 8]);
        GLL(b0 + k0, &Bs[(size_t)c0 * 8]);
        GLL(b1 + k0, &Bs[(size_t)c1 * 8]);
        __syncthreads();

        bfx8 af[4], bf[4];
        #pragma unroll
        for (int ii = 0; ii < 4; ii++)
            af[ii] = *(const bfx8*)(&As[(wm * 64 + ii * 16 + lo) * 32 + qd * 8]);
        #pragma unroll
        for (int jj = 0; jj < 4; jj++)
            bf[jj] = *(const bfx8*)(&Bs[(wn * 64 + jj * 16 + lo) * 32 + qd * 8]);
        #pragma unroll
        for (int ii = 0; ii < 4; ii++)
            #pragma unroll
            for (int jj = 0; jj < 4; jj++)
                acc[ii][jj] = __builtin_amdgcn_mfma_f32_16x16x32_bf16(af[ii], bf[jj], acc[ii][jj], 0, 0, 0);
        __syncthreads();
    }

    #pragma unroll
    for (int ii = 0; ii < 4; ii++)
        #pragma unroll
        for (int r = 0; r < 4; r++) {
            int row = m0 + wm * 64 + ii * 16 + qd * 4 + r;
            float linv = 1.0f / Lb[row];
            #pragma unroll
            for (int jj = 0; jj < 4; jj++) {
                int col = n0 + wn * 64 + jj * 16 + lo;
                Ob[(size_t)row * DIM + col] = acc[ii][jj][r] * linv;
            }
        }
}

// ---------------------------------------------------------------------------
// flash_attn: fallback (one WG per 32-row qtile) when ws is too small.
// ---------------------------------------------------------------------------
__global__ __launch_bounds__(512) void flash_attn(
    const u16* __restrict__ Q, const u16* __restrict__ Kmat,
    const u16* __restrict__ VT, float* __restrict__ O)
{
    int b = blockIdx.y;
    int qt = (int)(gridDim.x - 1) - (int)blockIdx.x;
    int q0 = qt * 32;
    int tid = threadIdx.x;
    int lane = tid & 63, w = tid >> 6;
    int lo = lane & 15, qd = lane >> 4;

    __shared__ __align__(16) float Sp[8][32][33];
    __shared__ __align__(16) __bf16 Pl[32][40];
    __shared__ float ml[32], ll[32], al[32];

    const u16* Qb = Q + (size_t)b * SEQ * DIM;
    const u16* Kb = Kmat + (size_t)b * SEQ * DIM;
    const u16* VTb = VT + (size_t)b * DIM * SEQ;

    bfx8 qf[2][4];
    #pragma unroll
    for (int i = 0; i < 2; i++)
        #pragma unroll
        for (int c = 0; c < 4; c++)
            qf[i][c] = *(const bfx8*)(Qb + (size_t)(q0 + i * 16 + lo) * DIM + w * 128 + c * 32 + qd * 8);

    fx4 oacc[2][8] = {};
    if (tid < 32) { ml[tid] = -INFINITY; ll[tid] = 0.0f; }
    __syncthreads();

    for (int kt = 0; kt <= qt; kt++) {
        int k0 = kt * 32;
        fx4 sp[2][2] = {};
        #pragma unroll
        for (int c = 0; c < 4; c++) {
            bfx8 kf[2];
            #pragma unroll
            for (int jn = 0; jn < 2; jn++)
                kf[jn] = *(const bfx8*)(Kb + (size_t)(k0 + jn * 16 + lo) * DIM + w * 128 + c * 32 + qd * 8);
            #pragma unroll
            for (int i = 0; i < 2; i++)
                #pragma unroll
                for (int jn = 0; jn < 2; jn++)
                    sp[i][jn] = __builtin_amdgcn_mfma_f32_16x16x32_bf16(qf[i][c], kf[jn], sp[i][jn], 0, 0, 0);
        }
        #pragma unroll
        for (int i = 0; i < 2; i++)
            #pragma unroll
            for (int jn = 0; jn < 2; jn++)
                #pragma unroll
                for (int r = 0; r < 4; r++)
                    Sp[w][i * 16 + qd * 4 + r][jn * 16 + lo] = sp[i][jn][r];
        __syncthreads();
        {
            int r = tid >> 4, ci = tid & 15;
            int q = q0 + r;
            float s0 = 0.0f, s1 = 0.0f;
            #pragma unroll
            for (int p = 0; p < 8; p++) { s0 += Sp[p][r][ci]; s1 += Sp[p][r][ci + 16]; }
            s0 = fminf(fmaxf(s0 * SCALE, -1e30f), 1e30f);
            s1 = fminf(fmaxf(s1 * SCALE, -1e30f), 1e30f);
            if (k0 + ci > q)      s0 = -INFINITY;
            if (k0 + ci + 16 > q) s1 = -INFINITY;
            float mx = fmaxf(s0, s1);
            #pragma unroll
            for (int off = 1; off < 16; off <<= 1) mx = fmaxf(mx, __shfl_xor(mx, off));
            float mo = ml[r];
            float mn = fmaxf(mo, mx);
            float p0 = __expf(s0 - mn), p1 = __expf(s1 - mn);
            Pl[r][ci] = (__bf16)p0;
            Pl[r][ci + 16] = (__bf16)p1;
            float ps = p0 + p1;
            #pragma unroll
            for (int off = 1; off < 16; off <<= 1) ps += __shfl_xor(ps, off);
            if (ci == 0) {
                float alpha = __expf(mo - mn);
                ll[r] = alpha * ll[r] + ps;
                ml[r] = mn;
                al[r] = alpha;
            }
        }
        __syncthreads();
        float alocal[2][4];
        #pragma unroll
        for (int i = 0; i < 2; i++)
            #pragma unroll
            for (int r = 0; r < 4; r++)
                alocal[i][r] = al[i * 16 + qd * 4 + r];
        #pragma unroll
        for (int i = 0; i < 2; i++)
            #pragma unroll
            for (int j = 0; j < 8; j++)
                #pragma unroll
                for (int r = 0; r < 4; r++)
                    oacc[i][j][r] *= alocal[i][r];
        bfx8 pf[2];
        #pragma unroll
        for (int i = 0; i < 2; i++)
            pf[i] = *(const bfx8*)(&Pl[i * 16 + lo][qd * 8]);
        #pragma unroll
        for (int j = 0; j < 8; j++) {
            bfx8 vf = *(const bfx8*)(VTb + (size_t)(w * 128 + j * 16 + lo) * SEQ + k0 + qd * 8);
            #pragma unroll
            for (int i = 0; i < 2; i++)
                oacc[i][j] = __builtin_amdgcn_mfma_f32_16x16x32_bf16(pf[i], vf, oacc[i][j], 0, 0, 0);
        }
    }

    float linv[2][4];
    #pragma unroll
    for (int i = 0; i < 2; i++)
        #pragma unroll
        for (int r = 0; r < 4; r++)
            linv[i][r] = 1.0f / ll[i * 16 + qd * 4 + r];
    float* Ob = O + (size_t)b * SEQ * DIM;
    #pragma unroll
    for (int i = 0; i < 2; i++)
        #pragma unroll
        for (int j = 0; j < 8; j++)
            #pragma unroll
            for (int r = 0; r < 4; r++) {
                int row = q0 + i * 16 + qd * 4 + r;
                int col = w * 128 + j * 16 + lo;
                Ob[(size_t)row * DIM + col] = oacc[i][j][r] * linv[i][r];
            }
}

// ---------------------------------------------------------------------------
extern "C" void kernel_launch(void* const* d_in, const int* in_sizes, int n_in,
                              void* d_out, int out_size, void* d_ws, size_t ws_size,
                              hipStream_t stream) {
    const float* x  = (const float*)d_in[0];
    const float* Wq = (const float*)d_in[1];
    const float* Wk = (const float*)d_in[2];
    const float* Wv = (const float*)d_in[3];

    u16* ws = (u16*)d_ws;
    u16* Qp  = ws;               // NEL bf16 (16 MiB)
    u16* Kp  = Qp + NEL;         // 16 MiB
    u16* VTp = Kp + NEL;         // 16 MiB
    // conversion staging (dead after gemm_fast) overlaps the P region
    u16* XBp = VTp + NEL;        // 16 MiB
    u16* WTp = XBp + NEL;        // 6 MiB
    // materialized P (all 4 batches) + Lrow
    u16*   Pm   = VTp + NEL;                                // 33.6 MiB
    float* Lrow = (float*)(Pm + (size_t)NBATCH * SEQ * SEQ);// 32 KiB

    size_t need_base = 3 * NEL * 2;                                   // 48 MiB
    size_t need_conv = NEL * 2 + (size_t)3 * 1024 * 1024 * 2;         // 22 MiB
    size_t need_mat  = (size_t)NBATCH * SEQ * SEQ * 2
                     + (size_t)NBATCH * SEQ * 4 + 1024;               // ~33.6 MiB
    bool fastg = ws_size >= need_base + need_conv;                    // 70 MiB
    bool mat   = ws_size >= need_base + need_mat;                     // ~82 MiB

    if (fastg && mat) {
        prep<<<dim3(11296), 256, 0, stream>>>(x, Wq, Wk, Wv, XBp, WTp, Lrow);
        gemm_fast<<<dim3(4, 64, 3), 256, 0, stream>>>(XBp, WTp, Qp, Kp, VTp);
        sgemm_exp<<<dim3(136, NBATCH), 256, 0, stream>>>(Qp, Kp, Pm, Lrow);
        pvgemm<<<dim3(128, NBATCH), 256, 0, stream>>>(Pm, VTp, Lrow, (float*)d_out);
    } else {
        gemm_legacy<<<dim3(8, 64, 3), 256, 0, stream>>>(x, Wq, Wk, Wv, Qp, Kp, VTp);
        flash_attn<<<dim3(SEQ / 32, NBATCH), 512, 0, stream>>>(
            Qp, Kp, VTp, (float*)d_out);
    }
}

// Round 10
// 255.373 us; speedup vs baseline: 2.1129x; 2.1129x over previous
//
#include <hip/hip_runtime.h>
#include <hip/hip_bf16.h>

typedef unsigned short u16;
typedef __bf16 bfx8 __attribute__((ext_vector_type(8)));
typedef float fx4 __attribute__((ext_vector_type(4)));

#define SEQ 2048
#define DIM 1024
#define NBATCH 4
#define SCALE 0.03125f  // 1/sqrt(1024)
#define NEL ((size_t)NBATCH * SEQ * DIM)   // 8388608 elems per Q/K/V

__device__ inline u16 f2bf(float f) {
    __bf16 h = (__bf16)f;
    return __builtin_bit_cast(unsigned short, h);
}

// async global->LDS, 16B per lane (dst must be wave-uniform base + lane*16)
#define GLL(gp, lp) __builtin_amdgcn_global_load_lds( \
    (const __attribute__((address_space(1))) unsigned int*)(gp), \
    (__attribute__((address_space(3))) unsigned int*)(lp), 16, 0, 0)

// ---------------------------------------------------------------------------
// prep: fused convert_x (blocks [0,8192)) + convert_w (blocks [8192,11264))
//       + zero Lrow (blocks [11264,11296)).  One dispatch instead of three.
// ---------------------------------------------------------------------------
__global__ __launch_bounds__(256) void prep(
    const float* __restrict__ X,
    const float* __restrict__ Wq, const float* __restrict__ Wk,
    const float* __restrict__ Wv,
    u16* __restrict__ XB, u16* __restrict__ WT, float* __restrict__ Lrow)
{
    __shared__ u16 t[32][33];
    int bid = blockIdx.x;
    int tid = threadIdx.x;
    if (bid < 8192) {
        size_t i = (size_t)bid * 256 + tid;
        float4 v = ((const float4*)X)[i];
        uint2 pk;
        pk.x = (unsigned)f2bf(v.x) | ((unsigned)f2bf(v.y) << 16);
        pk.y = (unsigned)f2bf(v.z) | ((unsigned)f2bf(v.w) << 16);
        ((uint2*)XB)[i] = pk;
    } else if (bid < 11264) {
        int tt = bid - 8192;
        int z = tt >> 10, t2 = tt & 1023;
        const float* W = (z == 0) ? Wq : (z == 1) ? Wk : Wv;
        u16* out = WT + (size_t)z * 1024 * 1024;
        int n0 = (t2 & 31) * 32, k0 = (t2 >> 5) * 32;
        int tx = tid & 31, ty = tid >> 5;
        #pragma unroll
        for (int i = 0; i < 32; i += 8)
            t[ty + i][tx] = f2bf(W[(size_t)(k0 + ty + i) * 1024 + n0 + tx]);
        __syncthreads();
        #pragma unroll
        for (int i = 0; i < 32; i += 8)
            out[(size_t)(n0 + ty + i) * 1024 + k0 + tx] = t[tx][ty + i];
    } else {
        int i = (bid - 11264) * 256 + tid;   // 8192 floats
        Lrow[i] = 0.0f;
    }
}

// ---------------------------------------------------------------------------
// gemm_fast: C = XB[8192,1024] x W (bf16, k-contig both sides).  GLL staging,
// 128x128 WG tile (r7's proven config: 77.5 us, VGPR 76, 4+ WG/CU).
// NOTE: do NOT grow the tile to 128x256 — the 128-AGPR accumulator then caps
// occupancy at 2 WG/CU (r8: 100 us), and __launch_bounds__ min-waves >= 4
// forces a catastrophic scratch spill (r9: 357 us, 1.8 GB scratch traffic).
// z==2 stores V transposed as VT[b][d][s].
// ---------------------------------------------------------------------------
__global__ __launch_bounds__(256) void gemm_fast(
    const u16* __restrict__ XB, const u16* __restrict__ WT,
    u16* __restrict__ Qo, u16* __restrict__ Ko, u16* __restrict__ VTo)
{
    const u16* Wz = WT + (size_t)blockIdx.z * 1024 * 1024;
    int m0 = blockIdx.y * 128, n0 = blockIdx.x * 128;

    __shared__ __align__(16) u16 As[128 * 32];
    __shared__ __align__(16) u16 Bs[128 * 32];
    __shared__ __align__(16) u16 Ct[64][132];

    int tid = threadIdx.x, lane = tid & 63, w = tid >> 6;
    int wm = w >> 1, wn = w & 1, lo = lane & 15, qd = lane >> 4;

    fx4 acc[4][4] = {};

    int c0 = tid, c1 = tid + 256;
    const u16* a0 = XB + (size_t)(m0 + (c0 >> 2)) * 1024 + (c0 & 3) * 8;
    const u16* a1 = XB + (size_t)(m0 + (c1 >> 2)) * 1024 + (c1 & 3) * 8;
    const u16* b0 = Wz + (size_t)(n0 + (c0 >> 2)) * 1024 + (c0 & 3) * 8;
    const u16* b1 = Wz + (size_t)(n0 + (c1 >> 2)) * 1024 + (c1 & 3) * 8;

    for (int k0 = 0; k0 < 1024; k0 += 32) {
        GLL(a0 + k0, &As[(size_t)c0 * 8]);
        GLL(a1 + k0, &As[(size_t)c1 * 8]);
        GLL(b0 + k0, &Bs[(size_t)c0 * 8]);
        GLL(b1 + k0, &Bs[(size_t)c1 * 8]);
        __syncthreads();

        bfx8 af[4], bf[4];
        #pragma unroll
        for (int i = 0; i < 4; i++)
            af[i] = *(const bfx8*)(&As[(wm * 64 + i * 16 + lo) * 32 + qd * 8]);
        #pragma unroll
        for (int j = 0; j < 4; j++)
            bf[j] = *(const bfx8*)(&Bs[(wn * 64 + j * 16 + lo) * 32 + qd * 8]);
        #pragma unroll
        for (int i = 0; i < 4; i++)
            #pragma unroll
            for (int j = 0; j < 4; j++)
                acc[i][j] = __builtin_amdgcn_mfma_f32_16x16x32_bf16(af[i], bf[j], acc[i][j], 0, 0, 0);
        __syncthreads();
    }

    if (blockIdx.z != 2) {
        u16* C = (blockIdx.z == 0) ? Qo : Ko;
        #pragma unroll
        for (int i = 0; i < 4; i++)
            #pragma unroll
            for (int j = 0; j < 4; j++)
                #pragma unroll
                for (int r = 0; r < 4; r++) {
                    int row = m0 + wm * 64 + i * 16 + qd * 4 + r;
                    int col = n0 + wn * 64 + j * 16 + lo;
                    C[(size_t)row * 1024 + col] = f2bf(acc[i][j][r]);
                }
    } else {
        #pragma unroll
        for (int half = 0; half < 2; half++) {
            __syncthreads();
            if (wm == half) {
                #pragma unroll
                for (int i = 0; i < 4; i++)
                    #pragma unroll
                    for (int j = 0; j < 4; j++)
                        #pragma unroll
                        for (int r = 0; r < 4; r++)
                            Ct[i * 16 + qd * 4 + r][wn * 64 + j * 16 + lo] = f2bf(acc[i][j][r]);
            }
            __syncthreads();
            #pragma unroll
            for (int e = tid; e < 64 * 128; e += 256) {
                int d = e >> 6, sl = e & 63;
                int gr = m0 + half * 64 + sl;
                int bb = gr >> 11, s = gr & 2047;
                VTo[((size_t)bb * DIM + (n0 + d)) * SEQ + s] = Ct[sl][d];
            }
        }
    }
}

// ---------------------------------------------------------------------------
// gemm_legacy: fp32-staging GEMM fallback (small ws).
// ---------------------------------------------------------------------------
__global__ __launch_bounds__(256) void gemm_legacy(
    const float* __restrict__ X,
    const float* __restrict__ Wq, const float* __restrict__ Wk, const float* __restrict__ Wv,
    u16* __restrict__ Qo, u16* __restrict__ Ko, u16* __restrict__ VTo)
{
    const int K = 1024, N = 1024;
    const float* W = (blockIdx.z == 0) ? Wq : (blockIdx.z == 1) ? Wk : Wv;
    int m0 = blockIdx.y * 128, n0 = blockIdx.x * 128;
    __shared__ __align__(16) u16 As[128 * 40];
    __shared__ __align__(16) u16 Bs[128 * 40];
    __shared__ __align__(16) u16 Ct[64][132];
    int tid = threadIdx.x, lane = tid & 63, w = tid >> 6;
    int wm = w >> 1, wn = w & 1, lo = lane & 15, qd = lane >> 4;
    fx4 acc[4][4] = {};
    for (int k0 = 0; k0 < K; k0 += 32) {
        #pragma unroll
        for (int c = tid; c < 1024; c += 256) {
            int row = c >> 3, cc = (c & 7) * 4;
            float4 v = *(const float4*)(X + (size_t)(m0 + row) * K + k0 + cc);
            uint2 pk;
            pk.x = (unsigned)f2bf(v.x) | ((unsigned)f2bf(v.y) << 16);
            pk.y = (unsigned)f2bf(v.z) | ((unsigned)f2bf(v.w) << 16);
            *(uint2*)(&As[row * 40 + cc]) = pk;
        }
        #pragma unroll
        for (int c = tid; c < 1024; c += 256) {
            int r = c >> 5, cc = (c & 31) * 4;
            float4 v = *(const float4*)(W + (size_t)(k0 + r) * N + n0 + cc);
            Bs[(cc + 0) * 40 + r] = f2bf(v.x);
            Bs[(cc + 1) * 40 + r] = f2bf(v.y);
            Bs[(cc + 2) * 40 + r] = f2bf(v.z);
            Bs[(cc + 3) * 40 + r] = f2bf(v.w);
        }
        __syncthreads();
        bfx8 af[4], bf[4];
        #pragma unroll
        for (int i = 0; i < 4; i++)
            af[i] = *(const bfx8*)(&As[(wm * 64 + i * 16 + lo) * 40 + qd * 8]);
        #pragma unroll
        for (int j = 0; j < 4; j++)
            bf[j] = *(const bfx8*)(&Bs[(wn * 64 + j * 16 + lo) * 40 + qd * 8]);
        #pragma unroll
        for (int i = 0; i < 4; i++)
            #pragma unroll
            for (int j = 0; j < 4; j++)
                acc[i][j] = __builtin_amdgcn_mfma_f32_16x16x32_bf16(af[i], bf[j], acc[i][j], 0, 0, 0);
        __syncthreads();
    }
    if (blockIdx.z != 2) {
        u16* C = (blockIdx.z == 0) ? Qo : Ko;
        #pragma unroll
        for (int i = 0; i < 4; i++)
            #pragma unroll
            for (int j = 0; j < 4; j++)
                #pragma unroll
                for (int r = 0; r < 4; r++) {
                    int row = m0 + wm * 64 + i * 16 + qd * 4 + r;
                    int col = n0 + wn * 64 + j * 16 + lo;
                    C[(size_t)row * N + col] = f2bf(acc[i][j][r]);
                }
    } else {
        #pragma unroll
        for (int half = 0; half < 2; half++) {
            __syncthreads();
            if (wm == half) {
                #pragma unroll
                for (int i = 0; i < 4; i++)
                    #pragma unroll
                    for (int j = 0; j < 4; j++)
                        #pragma unroll
                        for (int r = 0; r < 4; r++)
                            Ct[i * 16 + qd * 4 + r][wn * 64 + j * 16 + lo] = f2bf(acc[i][j][r]);
            }
            __syncthreads();
            #pragma unroll
            for (int e = tid; e < 64 * 128; e += 256) {
                int d = e >> 6, sl = e & 63;
                int gr = m0 + half * 64 + sl;
                int bb = gr >> 11, s = gr & 2047;
                VTo[((size_t)bb * DIM + (n0 + d)) * SEQ + s] = Ct[sl][d];
            }
        }
    }
}

// ---------------------------------------------------------------------------
// sgemm_exp: P[q][k] = exp(scale*(Q x K^T) masked), causal 128x128 tiles only,
// bf16 out, UNNORMALIZED (no max-subtraction; scores clamped +-30).
// Row sums accumulated into Lrow via atomicAdd.
// ---------------------------------------------------------------------------
__global__ __launch_bounds__(256) void sgemm_exp(
    const u16* __restrict__ Q, const u16* __restrict__ K,
    u16* __restrict__ P, float* __restrict__ Lrow)
{
    int b = blockIdx.y;
    int t = blockIdx.x;                  // 0..135 triangular tile
    int i = (int)((sqrtf(8.0f * t + 1.0f) - 1.0f) * 0.5f);
    while ((i + 1) * (i + 2) / 2 <= t) i++;
    while (i * (i + 1) / 2 > t) i--;
    int j = t - i * (i + 1) / 2;

    const u16* Qb = Q + (size_t)b * SEQ * DIM;
    const u16* Kb = K + (size_t)b * SEQ * DIM;
    u16* Pb = P + (size_t)b * SEQ * SEQ;
    float* Lb = Lrow + (size_t)b * SEQ;

    int m0 = i * 128, n0 = j * 128;

    __shared__ __align__(16) u16 As[128 * 32];
    __shared__ __align__(16) u16 Bs[128 * 32];

    int tid = threadIdx.x, lane = tid & 63, w = tid >> 6;
    int wm = w >> 1, wn = w & 1, lo = lane & 15, qd = lane >> 4;

    fx4 acc[4][4] = {};

    int c0 = tid, c1 = tid + 256;
    const u16* a0 = Qb + (size_t)(m0 + (c0 >> 2)) * DIM + (c0 & 3) * 8;
    const u16* a1 = Qb + (size_t)(m0 + (c1 >> 2)) * DIM + (c1 & 3) * 8;
    const u16* b0 = Kb + (size_t)(n0 + (c0 >> 2)) * DIM + (c0 & 3) * 8;
    const u16* b1 = Kb + (size_t)(n0 + (c1 >> 2)) * DIM + (c1 & 3) * 8;

    for (int k0 = 0; k0 < 1024; k0 += 32) {
        GLL(a0 + k0, &As[(size_t)c0 * 8]);
        GLL(a1 + k0, &As[(size_t)c1 * 8]);
        GLL(b0 + k0, &Bs[(size_t)c0 * 8]);
        GLL(b1 + k0, &Bs[(size_t)c1 * 8]);
        __syncthreads();

        bfx8 af[4], bf[4];
        #pragma unroll
        for (int ii = 0; ii < 4; ii++)
            af[ii] = *(const bfx8*)(&As[(wm * 64 + ii * 16 + lo) * 32 + qd * 8]);
        #pragma unroll
        for (int jj = 0; jj < 4; jj++)
            bf[jj] = *(const bfx8*)(&Bs[(wn * 64 + jj * 16 + lo) * 32 + qd * 8]);
        #pragma unroll
        for (int ii = 0; ii < 4; ii++)
            #pragma unroll
            for (int jj = 0; jj < 4; jj++)
                acc[ii][jj] = __builtin_amdgcn_mfma_f32_16x16x32_bf16(af[ii], bf[jj], acc[ii][jj], 0, 0, 0);
        __syncthreads();
    }

    #pragma unroll
    for (int ii = 0; ii < 4; ii++)
        #pragma unroll
        for (int r = 0; r < 4; r++) {
            int row = m0 + wm * 64 + ii * 16 + qd * 4 + r;
            float rs = 0.0f;
            #pragma unroll
            for (int jj = 0; jj < 4; jj++) {
                int col = n0 + wn * 64 + jj * 16 + lo;
                float s = acc[ii][jj][r] * SCALE;
                s = fminf(fmaxf(s, -30.0f), 30.0f);
                float p = (col > row) ? 0.0f : __expf(s);
                Pb[(size_t)row * SEQ + col] = f2bf(p);
                rs += p;
            }
            #pragma unroll
            for (int off = 1; off < 16; off <<= 1) rs += __shfl_xor(rs, off);
            if (lo == 0) atomicAdd(&Lb[row], rs);
        }
}

// ---------------------------------------------------------------------------
// pvgemm: O[q][d] = P[q][k] x VT[d][k] / L[q].  Triangular k-extent per
// q-block; biggest q-blocks dispatched first.  Both operands key-contiguous.
// ---------------------------------------------------------------------------
__global__ __launch_bounds__(256) void pvgemm(
    const u16* __restrict__ P, const u16* __restrict__ VT,
    const float* __restrict__ Lrow, float* __restrict__ O)
{
    int b = blockIdx.y;
    int qb = 15 - (int)(blockIdx.x >> 3);   // big k-extent first
    int db = blockIdx.x & 7;
    int m0 = qb * 128, n0 = db * 128;
    int kext = (qb + 1) * 128;

    const u16* Pb = P + (size_t)b * SEQ * SEQ;
    const u16* Vb = VT + (size_t)b * DIM * SEQ;
    const float* Lb = Lrow + (size_t)b * SEQ;
    float* Ob = O + (size_t)b * SEQ * DIM;

    __shared__ __align__(16) u16 As[128 * 32];
    __shared__ __align__(16) u16 Bs[128 * 32];

    int tid = threadIdx.x, lane = tid & 63, w = tid >> 6;
    int wm = w >> 1, wn = w & 1, lo = lane & 15, qd = lane >> 4;

    fx4 acc[4][4] = {};

    int c0 = tid, c1 = tid + 256;
    const u16* a0 = Pb + (size_t)(m0 + (c0 >> 2)) * SEQ + (c0 & 3) * 8;
    const u16* a1 = Pb + (size_t)(m0 + (c1 >> 2)) * SEQ + (c1 & 3) * 8;
    const u16* b0 = Vb + (size_t)(n0 + (c0 >> 2)) * SEQ + (c0 & 3) * 8;
    const u16* b1 = Vb + (size_t)(n0 + (c1 >> 2)) * SEQ + (c1 & 3) * 8;

    for (int k0 = 0; k0 < kext; k0 += 32) {
        GLL(a0 + k0, &As[(size_t)c0 * 8]);
        GLL(a1 + k0, &As[(size_t)c1 * 8]);
        GLL(b0 + k0, &Bs[(size_t)c0 * 8]);
        GLL(b1 + k0, &Bs[(size_t)c1 * 8]);
        __syncthreads();

        bfx8 af[4], bf[4];
        #pragma unroll
        for (int ii = 0; ii < 4; ii++)
            af[ii] = *(const bfx8*)(&As[(wm * 64 + ii * 16 + lo) * 32 + qd * 8]);
        #pragma unroll
        for (int jj = 0; jj < 4; jj++)
            bf[jj] = *(const bfx8*)(&Bs[(wn * 64 + jj * 16 + lo) * 32 + qd * 8]);
        #pragma unroll
        for (int ii = 0; ii < 4; ii++)
            #pragma unroll
            for (int jj = 0; jj < 4; jj++)
                acc[ii][jj] = __builtin_amdgcn_mfma_f32_16x16x32_bf16(af[ii], bf[jj], acc[ii][jj], 0, 0, 0);
        __syncthreads();
    }

    #pragma unroll
    for (int ii = 0; ii < 4; ii++)
        #pragma unroll
        for (int r = 0; r < 4; r++) {
            int row = m0 + wm * 64 + ii * 16 + qd * 4 + r;
            float linv = 1.0f / Lb[row];
            #pragma unroll
            for (int jj = 0; jj < 4; jj++) {
                int col = n0 + wn * 64 + jj * 16 + lo;
                Ob[(size_t)row * DIM + col] = acc[ii][jj][r] * linv;
            }
        }
}

// ---------------------------------------------------------------------------
// flash_attn: fallback (one WG per 32-row qtile) when ws is too small.
// ---------------------------------------------------------------------------
__global__ __launch_bounds__(512) void flash_attn(
    const u16* __restrict__ Q, const u16* __restrict__ Kmat,
    const u16* __restrict__ VT, float* __restrict__ O)
{
    int b = blockIdx.y;
    int qt = (int)(gridDim.x - 1) - (int)blockIdx.x;
    int q0 = qt * 32;
    int tid = threadIdx.x;
    int lane = tid & 63, w = tid >> 6;
    int lo = lane & 15, qd = lane >> 4;

    __shared__ __align__(16) float Sp[8][32][33];
    __shared__ __align__(16) __bf16 Pl[32][40];
    __shared__ float ml[32], ll[32], al[32];

    const u16* Qb = Q + (size_t)b * SEQ * DIM;
    const u16* Kb = Kmat + (size_t)b * SEQ * DIM;
    const u16* VTb = VT + (size_t)b * DIM * SEQ;

    bfx8 qf[2][4];
    #pragma unroll
    for (int i = 0; i < 2; i++)
        #pragma unroll
        for (int c = 0; c < 4; c++)
            qf[i][c] = *(const bfx8*)(Qb + (size_t)(q0 + i * 16 + lo) * DIM + w * 128 + c * 32 + qd * 8);

    fx4 oacc[2][8] = {};
    if (tid < 32) { ml[tid] = -INFINITY; ll[tid] = 0.0f; }
    __syncthreads();

    for (int kt = 0; kt <= qt; kt++) {
        int k0 = kt * 32;
        fx4 sp[2][2] = {};
        #pragma unroll
        for (int c = 0; c < 4; c++) {
            bfx8 kf[2];
            #pragma unroll
            for (int jn = 0; jn < 2; jn++)
                kf[jn] = *(const bfx8*)(Kb + (size_t)(k0 + jn * 16 + lo) * DIM + w * 128 + c * 32 + qd * 8);
            #pragma unroll
            for (int i = 0; i < 2; i++)
                #pragma unroll
                for (int jn = 0; jn < 2; jn++)
                    sp[i][jn] = __builtin_amdgcn_mfma_f32_16x16x32_bf16(qf[i][c], kf[jn], sp[i][jn], 0, 0, 0);
        }
        #pragma unroll
        for (int i = 0; i < 2; i++)
            #pragma unroll
            for (int jn = 0; jn < 2; jn++)
                #pragma unroll
                for (int r = 0; r < 4; r++)
                    Sp[w][i * 16 + qd * 4 + r][jn * 16 + lo] = sp[i][jn][r];
        __syncthreads();
        {
            int r = tid >> 4, ci = tid & 15;
            int q = q0 + r;
            float s0 = 0.0f, s1 = 0.0f;
            #pragma unroll
            for (int p = 0; p < 8; p++) { s0 += Sp[p][r][ci]; s1 += Sp[p][r][ci + 16]; }
            s0 = fminf(fmaxf(s0 * SCALE, -1e30f), 1e30f);
            s1 = fminf(fmaxf(s1 * SCALE, -1e30f), 1e30f);
            if (k0 + ci > q)      s0 = -INFINITY;
            if (k0 + ci + 16 > q) s1 = -INFINITY;
            float mx = fmaxf(s0, s1);
            #pragma unroll
            for (int off = 1; off < 16; off <<= 1) mx = fmaxf(mx, __shfl_xor(mx, off));
            float mo = ml[r];
            float mn = fmaxf(mo, mx);
            float p0 = __expf(s0 - mn), p1 = __expf(s1 - mn);
            Pl[r][ci] = (__bf16)p0;
            Pl[r][ci + 16] = (__bf16)p1;
            float ps = p0 + p1;
            #pragma unroll
            for (int off = 1; off < 16; off <<= 1) ps += __shfl_xor(ps, off);
            if (ci == 0) {
                float alpha = __expf(mo - mn);
                ll[r] = alpha * ll[r] + ps;
                ml[r] = mn;
                al[r] = alpha;
            }
        }
        __syncthreads();
        float alocal[2][4];
        #pragma unroll
        for (int i = 0; i < 2; i++)
            #pragma unroll
            for (int r = 0; r < 4; r++)
                alocal[i][r] = al[i * 16 + qd * 4 + r];
        #pragma unroll
        for (int i = 0; i < 2; i++)
            #pragma unroll
            for (int j = 0; j < 8; j++)
                #pragma unroll
                for (int r = 0; r < 4; r++)
                    oacc[i][j][r] *= alocal[i][r];
        bfx8 pf[2];
        #pragma unroll
        for (int i = 0; i < 2; i++)
            pf[i] = *(const bfx8*)(&Pl[i * 16 + lo][qd * 8]);
        #pragma unroll
        for (int j = 0; j < 8; j++) {
            bfx8 vf = *(const bfx8*)(VTb + (size_t)(w * 128 + j * 16 + lo) * SEQ + k0 + qd * 8);
            #pragma unroll
            for (int i = 0; i < 2; i++)
                oacc[i][j] = __builtin_amdgcn_mfma_f32_16x16x32_bf16(pf[i], vf, oacc[i][j], 0, 0, 0);
        }
    }

    float linv[2][4];
    #pragma unroll
    for (int i = 0; i < 2; i++)
        #pragma unroll
        for (int r = 0; r < 4; r++)
            linv[i][r] = 1.0f / ll[i * 16 + qd * 4 + r];
    float* Ob = O + (size_t)b * SEQ * DIM;
    #pragma unroll
    for (int i = 0; i < 2; i++)
        #pragma unroll
        for (int j = 0; j < 8; j++)
            #pragma unroll
            for (int r = 0; r < 4; r++) {
                int row = q0 + i * 16 + qd * 4 + r;
                int col = w * 128 + j * 16 + lo;
                Ob[(size_t)row * DIM + col] = oacc[i][j][r] * linv[i][r];
            }
}

// ---------------------------------------------------------------------------
extern "C" void kernel_launch(void* const* d_in, const int* in_sizes, int n_in,
                              void* d_out, int out_size, void* d_ws, size_t ws_size,
                              hipStream_t stream) {
    const float* x  = (const float*)d_in[0];
    const float* Wq = (const float*)d_in[1];
    const float* Wk = (const float*)d_in[2];
    const float* Wv = (const float*)d_in[3];

    u16* ws = (u16*)d_ws;
    u16* Qp  = ws;               // NEL bf16 (16 MiB)
    u16* Kp  = Qp + NEL;         // 16 MiB
    u16* VTp = Kp + NEL;         // 16 MiB
    // conversion staging (dead after gemm_fast) overlaps the P region
    u16* XBp = VTp + NEL;        // 16 MiB
    u16* WTp = XBp + NEL;        // 6 MiB
    // materialized P (all 4 batches) + Lrow
    u16*   Pm   = VTp + NEL;                                // 33.6 MiB
    float* Lrow = (float*)(Pm + (size_t)NBATCH * SEQ * SEQ);// 32 KiB

    size_t need_base = 3 * NEL * 2;                                   // 48 MiB
    size_t need_conv = NEL * 2 + (size_t)3 * 1024 * 1024 * 2;         // 22 MiB
    size_t need_mat  = (size_t)NBATCH * SEQ * SEQ * 2
                     + (size_t)NBATCH * SEQ * 4 + 1024;               // ~33.6 MiB
    bool fastg = ws_size >= need_base + need_conv;                    // 70 MiB
    bool mat   = ws_size >= need_base + need_mat;                     // ~82 MiB

    if (fastg && mat) {
        prep<<<dim3(11296), 256, 0, stream>>>(x, Wq, Wk, Wv, XBp, WTp, Lrow);
        gemm_fast<<<dim3(8, 64, 3), 256, 0, stream>>>(XBp, WTp, Qp, Kp, VTp);
        sgemm_exp<<<dim3(136, NBATCH), 256, 0, stream>>>(Qp, Kp, Pm, Lrow);
        pvgemm<<<dim3(128, NBATCH), 256, 0, stream>>>(Pm, VTp, Lrow, (float*)d_out);
    } else {
        gemm_legacy<<<dim3(8, 64, 3), 256, 0, stream>>>(x, Wq, Wk, Wv, Qp, Kp, VTp);
        flash_attn<<<dim3(SEQ / 32, NBATCH), 512, 0, stream>>>(
            Qp, Kp, VTp, (float*)d_out);
    }
}

// Round 11
// 255.095 us; speedup vs baseline: 2.1152x; 1.0011x over previous
//
#include <hip/hip_runtime.h>
#include <hip/hip_bf16.h>

typedef unsigned short u16;
typedef __bf16 bfx8 __attribute__((ext_vector_type(8)));
typedef float fx4 __attribute__((ext_vector_type(4)));

#define SEQ 2048
#define DIM 1024
#define NBATCH 4
#define SCALE 0.03125f  // 1/sqrt(1024)
#define NEL ((size_t)NBATCH * SEQ * DIM)   // 8388608 elems per Q/K/V

__device__ inline u16 f2bf(float f) {
    __bf16 h = (__bf16)f;
    return __builtin_bit_cast(unsigned short, h);
}

// async global->LDS, 16B per lane (dst must be wave-uniform base + lane*16)
#define GLL(gp, lp) __builtin_amdgcn_global_load_lds( \
    (const __attribute__((address_space(1))) unsigned int*)(gp), \
    (__attribute__((address_space(3))) unsigned int*)(lp), 16, 0, 0)

// ---------------------------------------------------------------------------
// prep: fused convert_x (blocks [0,8192)) + convert_w (blocks [8192,11264))
//       + zero Lrow (blocks [11264,11296)).  One dispatch instead of three.
// ---------------------------------------------------------------------------
__global__ __launch_bounds__(256) void prep(
    const float* __restrict__ X,
    const float* __restrict__ Wq, const float* __restrict__ Wk,
    const float* __restrict__ Wv,
    u16* __restrict__ XB, u16* __restrict__ WT, float* __restrict__ Lrow)
{
    __shared__ u16 t[32][33];
    int bid = blockIdx.x;
    int tid = threadIdx.x;
    if (bid < 8192) {
        size_t i = (size_t)bid * 256 + tid;
        float4 v = ((const float4*)X)[i];
        uint2 pk;
        pk.x = (unsigned)f2bf(v.x) | ((unsigned)f2bf(v.y) << 16);
        pk.y = (unsigned)f2bf(v.z) | ((unsigned)f2bf(v.w) << 16);
        ((uint2*)XB)[i] = pk;
    } else if (bid < 11264) {
        int tt = bid - 8192;
        int z = tt >> 10, t2 = tt & 1023;
        const float* W = (z == 0) ? Wq : (z == 1) ? Wk : Wv;
        u16* out = WT + (size_t)z * 1024 * 1024;
        int n0 = (t2 & 31) * 32, k0 = (t2 >> 5) * 32;
        int tx = tid & 31, ty = tid >> 5;
        #pragma unroll
        for (int i = 0; i < 32; i += 8)
            t[ty + i][tx] = f2bf(W[(size_t)(k0 + ty + i) * 1024 + n0 + tx]);
        __syncthreads();
        #pragma unroll
        for (int i = 0; i < 32; i += 8)
            out[(size_t)(n0 + ty + i) * 1024 + k0 + tx] = t[tx][ty + i];
    } else {
        int i = (bid - 11264) * 256 + tid;   // 8192 floats
        Lrow[i] = 0.0f;
    }
}

// ---------------------------------------------------------------------------
// gemm_fast: C = XB[8192,1024] x W (bf16, k-contig both sides).  GLL staging,
// 128x128 WG tile (proven: 77.5 us, VGPR 76, 4 WG/CU).
// NOTE: do NOT grow the tile to 128x256 — the 128-AGPR accumulator caps
// occupancy at 2 WG/CU (r8: 100 us); __launch_bounds__ min-waves >= 4 on it
// forces a catastrophic scratch spill (r9: 357 us, 1.8 GB scratch traffic).
// z==2 stores V transposed as VT[b][d][s].
// ---------------------------------------------------------------------------
__global__ __launch_bounds__(256) void gemm_fast(
    const u16* __restrict__ XB, const u16* __restrict__ WT,
    u16* __restrict__ Qo, u16* __restrict__ Ko, u16* __restrict__ VTo)
{
    const u16* Wz = WT + (size_t)blockIdx.z * 1024 * 1024;
    int m0 = blockIdx.y * 128, n0 = blockIdx.x * 128;

    __shared__ __align__(16) u16 As[128 * 32];
    __shared__ __align__(16) u16 Bs[128 * 32];
    __shared__ __align__(16) u16 Ct[64][132];

    int tid = threadIdx.x, lane = tid & 63, w = tid >> 6;
    int wm = w >> 1, wn = w & 1, lo = lane & 15, qd = lane >> 4;

    fx4 acc[4][4] = {};

    int c0 = tid, c1 = tid + 256;
    const u16* a0 = XB + (size_t)(m0 + (c0 >> 2)) * 1024 + (c0 & 3) * 8;
    const u16* a1 = XB + (size_t)(m0 + (c1 >> 2)) * 1024 + (c1 & 3) * 8;
    const u16* b0 = Wz + (size_t)(n0 + (c0 >> 2)) * 1024 + (c0 & 3) * 8;
    const u16* b1 = Wz + (size_t)(n0 + (c1 >> 2)) * 1024 + (c1 & 3) * 8;

    for (int k0 = 0; k0 < 1024; k0 += 32) {
        GLL(a0 + k0, &As[(size_t)c0 * 8]);
        GLL(a1 + k0, &As[(size_t)c1 * 8]);
        GLL(b0 + k0, &Bs[(size_t)c0 * 8]);
        GLL(b1 + k0, &Bs[(size_t)c1 * 8]);
        __syncthreads();

        bfx8 af[4], bf[4];
        #pragma unroll
        for (int i = 0; i < 4; i++)
            af[i] = *(const bfx8*)(&As[(wm * 64 + i * 16 + lo) * 32 + qd * 8]);
        #pragma unroll
        for (int j = 0; j < 4; j++)
            bf[j] = *(const bfx8*)(&Bs[(wn * 64 + j * 16 + lo) * 32 + qd * 8]);
        #pragma unroll
        for (int i = 0; i < 4; i++)
            #pragma unroll
            for (int j = 0; j < 4; j++)
                acc[i][j] = __builtin_amdgcn_mfma_f32_16x16x32_bf16(af[i], bf[j], acc[i][j], 0, 0, 0);
        __syncthreads();
    }

    if (blockIdx.z != 2) {
        u16* C = (blockIdx.z == 0) ? Qo : Ko;
        #pragma unroll
        for (int i = 0; i < 4; i++)
            #pragma unroll
            for (int j = 0; j < 4; j++)
                #pragma unroll
                for (int r = 0; r < 4; r++) {
                    int row = m0 + wm * 64 + i * 16 + qd * 4 + r;
                    int col = n0 + wn * 64 + j * 16 + lo;
                    C[(size_t)row * 1024 + col] = f2bf(acc[i][j][r]);
                }
    } else {
        #pragma unroll
        for (int half = 0; half < 2; half++) {
            __syncthreads();
            if (wm == half) {
                #pragma unroll
                for (int i = 0; i < 4; i++)
                    #pragma unroll
                    for (int j = 0; j < 4; j++)
                        #pragma unroll
                        for (int r = 0; r < 4; r++)
                            Ct[i * 16 + qd * 4 + r][wn * 64 + j * 16 + lo] = f2bf(acc[i][j][r]);
            }
            __syncthreads();
            #pragma unroll
            for (int e = tid; e < 64 * 128; e += 256) {
                int d = e >> 6, sl = e & 63;
                int gr = m0 + half * 64 + sl;
                int bb = gr >> 11, s = gr & 2047;
                VTo[((size_t)bb * DIM + (n0 + d)) * SEQ + s] = Ct[sl][d];
            }
        }
    }
}

// ---------------------------------------------------------------------------
// gemm_legacy: fp32-staging GEMM fallback (small ws).
// ---------------------------------------------------------------------------
__global__ __launch_bounds__(256) void gemm_legacy(
    const float* __restrict__ X,
    const float* __restrict__ Wq, const float* __restrict__ Wk, const float* __restrict__ Wv,
    u16* __restrict__ Qo, u16* __restrict__ Ko, u16* __restrict__ VTo)
{
    const int K = 1024, N = 1024;
    const float* W = (blockIdx.z == 0) ? Wq : (blockIdx.z == 1) ? Wk : Wv;
    int m0 = blockIdx.y * 128, n0 = blockIdx.x * 128;
    __shared__ __align__(16) u16 As[128 * 40];
    __shared__ __align__(16) u16 Bs[128 * 40];
    __shared__ __align__(16) u16 Ct[64][132];
    int tid = threadIdx.x, lane = tid & 63, w = tid >> 6;
    int wm = w >> 1, wn = w & 1, lo = lane & 15, qd = lane >> 4;
    fx4 acc[4][4] = {};
    for (int k0 = 0; k0 < K; k0 += 32) {
        #pragma unroll
        for (int c = tid; c < 1024; c += 256) {
            int row = c >> 3, cc = (c & 7) * 4;
            float4 v = *(const float4*)(X + (size_t)(m0 + row) * K + k0 + cc);
            uint2 pk;
            pk.x = (unsigned)f2bf(v.x) | ((unsigned)f2bf(v.y) << 16);
            pk.y = (unsigned)f2bf(v.z) | ((unsigned)f2bf(v.w) << 16);
            *(uint2*)(&As[row * 40 + cc]) = pk;
        }
        #pragma unroll
        for (int c = tid; c < 1024; c += 256) {
            int r = c >> 5, cc = (c & 31) * 4;
            float4 v = *(const float4*)(W + (size_t)(k0 + r) * N + n0 + cc);
            Bs[(cc + 0) * 40 + r] = f2bf(v.x);
            Bs[(cc + 1) * 40 + r] = f2bf(v.y);
            Bs[(cc + 2) * 40 + r] = f2bf(v.z);
            Bs[(cc + 3) * 40 + r] = f2bf(v.w);
        }
        __syncthreads();
        bfx8 af[4], bf[4];
        #pragma unroll
        for (int i = 0; i < 4; i++)
            af[i] = *(const bfx8*)(&As[(wm * 64 + i * 16 + lo) * 40 + qd * 8]);
        #pragma unroll
        for (int j = 0; j < 4; j++)
            bf[j] = *(const bfx8*)(&Bs[(wn * 64 + j * 16 + lo) * 40 + qd * 8]);
        #pragma unroll
        for (int i = 0; i < 4; i++)
            #pragma unroll
            for (int j = 0; j < 4; j++)
                acc[i][j] = __builtin_amdgcn_mfma_f32_16x16x32_bf16(af[i], bf[j], acc[i][j], 0, 0, 0);
        __syncthreads();
    }
    if (blockIdx.z != 2) {
        u16* C = (blockIdx.z == 0) ? Qo : Ko;
        #pragma unroll
        for (int i = 0; i < 4; i++)
            #pragma unroll
            for (int j = 0; j < 4; j++)
                #pragma unroll
                for (int r = 0; r < 4; r++) {
                    int row = m0 + wm * 64 + i * 16 + qd * 4 + r;
                    int col = n0 + wn * 64 + j * 16 + lo;
                    C[(size_t)row * N + col] = f2bf(acc[i][j][r]);
                }
    } else {
        #pragma unroll
        for (int half = 0; half < 2; half++) {
            __syncthreads();
            if (wm == half) {
                #pragma unroll
                for (int i = 0; i < 4; i++)
                    #pragma unroll
                    for (int j = 0; j < 4; j++)
                        #pragma unroll
                        for (int r = 0; r < 4; r++)
                            Ct[i * 16 + qd * 4 + r][wn * 64 + j * 16 + lo] = f2bf(acc[i][j][r]);
            }
            __syncthreads();
            #pragma unroll
            for (int e = tid; e < 64 * 128; e += 256) {
                int d = e >> 6, sl = e & 63;
                int gr = m0 + half * 64 + sl;
                int bb = gr >> 11, s = gr & 2047;
                VTo[((size_t)bb * DIM + (n0 + d)) * SEQ + s] = Ct[sl][d];
            }
        }
    }
}

// ---------------------------------------------------------------------------
// sgemm_exp: P[q][k] = exp(scale*(Q x K^T) masked), causal 128x128 tiles,
// bf16 out, UNNORMALIZED (no max-subtraction; scores clamped +-30).
// 512 threads / 8 waves (2m x 4n; each wave 64 rows x 32 cols, acc 4x2):
// grid is only ~2.1 WG/CU, so doubling waves/WG doubles waves/CU (~17) to
// hide the staging-drain latency that capped the 256-thread version.
// Row sums accumulated into Lrow via atomicAdd.
// ---------------------------------------------------------------------------
__global__ __launch_bounds__(512) void sgemm_exp(
    const u16* __restrict__ Q, const u16* __restrict__ K,
    u16* __restrict__ P, float* __restrict__ Lrow)
{
    int b = blockIdx.y;
    int t = blockIdx.x;                  // 0..135 triangular tile
    int i = (int)((sqrtf(8.0f * t + 1.0f) - 1.0f) * 0.5f);
    while ((i + 1) * (i + 2) / 2 <= t) i++;
    while (i * (i + 1) / 2 > t) i--;
    int j = t - i * (i + 1) / 2;

    const u16* Qb = Q + (size_t)b * SEQ * DIM;
    const u16* Kb = K + (size_t)b * SEQ * DIM;
    u16* Pb = P + (size_t)b * SEQ * SEQ;
    float* Lb = Lrow + (size_t)b * SEQ;

    int m0 = i * 128, n0 = j * 128;

    __shared__ __align__(16) u16 As[128 * 32];
    __shared__ __align__(16) u16 Bs[128 * 32];

    int tid = threadIdx.x, lane = tid & 63, w = tid >> 6;
    int wm = w >> 2, wn = w & 3, lo = lane & 15, qd = lane >> 4;

    fx4 acc[4][2] = {};

    int c0 = tid;                         // 512 chunks of 16B each per operand
    const u16* a0 = Qb + (size_t)(m0 + (c0 >> 2)) * DIM + (c0 & 3) * 8;
    const u16* b0 = Kb + (size_t)(n0 + (c0 >> 2)) * DIM + (c0 & 3) * 8;

    for (int k0 = 0; k0 < 1024; k0 += 32) {
        GLL(a0 + k0, &As[(size_t)c0 * 8]);
        GLL(b0 + k0, &Bs[(size_t)c0 * 8]);
        __syncthreads();

        bfx8 af[4], bf[2];
        #pragma unroll
        for (int ii = 0; ii < 4; ii++)
            af[ii] = *(const bfx8*)(&As[(wm * 64 + ii * 16 + lo) * 32 + qd * 8]);
        #pragma unroll
        for (int jn = 0; jn < 2; jn++)
            bf[jn] = *(const bfx8*)(&Bs[(wn * 32 + jn * 16 + lo) * 32 + qd * 8]);
        #pragma unroll
        for (int ii = 0; ii < 4; ii++)
            #pragma unroll
            for (int jn = 0; jn < 2; jn++)
                acc[ii][jn] = __builtin_amdgcn_mfma_f32_16x16x32_bf16(af[ii], bf[jn], acc[ii][jn], 0, 0, 0);
        __syncthreads();
    }

    #pragma unroll
    for (int ii = 0; ii < 4; ii++)
        #pragma unroll
        for (int r = 0; r < 4; r++) {
            int row = m0 + wm * 64 + ii * 16 + qd * 4 + r;
            float rs = 0.0f;
            #pragma unroll
            for (int jn = 0; jn < 2; jn++) {
                int col = n0 + wn * 32 + jn * 16 + lo;
                float s = acc[ii][jn][r] * SCALE;
                s = fminf(fmaxf(s, -30.0f), 30.0f);
                float p = (col > row) ? 0.0f : __expf(s);
                Pb[(size_t)row * SEQ + col] = f2bf(p);
                rs += p;
            }
            #pragma unroll
            for (int off = 1; off < 16; off <<= 1) rs += __shfl_xor(rs, off);
            if (lo == 0) atomicAdd(&Lb[row], rs);
        }
}

// ---------------------------------------------------------------------------
// pvgemm: O[q][d] = P[q][k] x VT[d][k] / L[q].  Triangular k-extent per
// q-block; biggest q-blocks dispatched first.  512 threads / 8 waves
// (2m x 4n), same rationale as sgemm_exp.
// ---------------------------------------------------------------------------
__global__ __launch_bounds__(512) void pvgemm(
    const u16* __restrict__ P, const u16* __restrict__ VT,
    const float* __restrict__ Lrow, float* __restrict__ O)
{
    int b = blockIdx.y;
    int qb = 15 - (int)(blockIdx.x >> 3);   // big k-extent first
    int db = blockIdx.x & 7;
    int m0 = qb * 128, n0 = db * 128;
    int kext = (qb + 1) * 128;

    const u16* Pb = P + (size_t)b * SEQ * SEQ;
    const u16* Vb = VT + (size_t)b * DIM * SEQ;
    const float* Lb = Lrow + (size_t)b * SEQ;
    float* Ob = O + (size_t)b * SEQ * DIM;

    __shared__ __align__(16) u16 As[128 * 32];
    __shared__ __align__(16) u16 Bs[128 * 32];

    int tid = threadIdx.x, lane = tid & 63, w = tid >> 6;
    int wm = w >> 2, wn = w & 3, lo = lane & 15, qd = lane >> 4;

    fx4 acc[4][2] = {};

    int c0 = tid;
    const u16* a0 = Pb + (size_t)(m0 + (c0 >> 2)) * SEQ + (c0 & 3) * 8;
    const u16* b0 = Vb + (size_t)(n0 + (c0 >> 2)) * SEQ + (c0 & 3) * 8;

    for (int k0 = 0; k0 < kext; k0 += 32) {
        GLL(a0 + k0, &As[(size_t)c0 * 8]);
        GLL(b0 + k0, &Bs[(size_t)c0 * 8]);
        __syncthreads();

        bfx8 af[4], bf[2];
        #pragma unroll
        for (int ii = 0; ii < 4; ii++)
            af[ii] = *(const bfx8*)(&As[(wm * 64 + ii * 16 + lo) * 32 + qd * 8]);
        #pragma unroll
        for (int jn = 0; jn < 2; jn++)
            bf[jn] = *(const bfx8*)(&Bs[(wn * 32 + jn * 16 + lo) * 32 + qd * 8]);
        #pragma unroll
        for (int ii = 0; ii < 4; ii++)
            #pragma unroll
            for (int jn = 0; jn < 2; jn++)
                acc[ii][jn] = __builtin_amdgcn_mfma_f32_16x16x32_bf16(af[ii], bf[jn], acc[ii][jn], 0, 0, 0);
        __syncthreads();
    }

    #pragma unroll
    for (int ii = 0; ii < 4; ii++)
        #pragma unroll
        for (int r = 0; r < 4; r++) {
            int row = m0 + wm * 64 + ii * 16 + qd * 4 + r;
            float linv = 1.0f / Lb[row];
            #pragma unroll
            for (int jn = 0; jn < 2; jn++) {
                int col = n0 + wn * 32 + jn * 16 + lo;
                Ob[(size_t)row * DIM + col] = acc[ii][jn][r] * linv;
            }
        }
}

// ---------------------------------------------------------------------------
// flash_attn: fallback (one WG per 32-row qtile) when ws is too small.
// ---------------------------------------------------------------------------
__global__ __launch_bounds__(512) void flash_attn(
    const u16* __restrict__ Q, const u16* __restrict__ Kmat,
    const u16* __restrict__ VT, float* __restrict__ O)
{
    int b = blockIdx.y;
    int qt = (int)(gridDim.x - 1) - (int)blockIdx.x;
    int q0 = qt * 32;
    int tid = threadIdx.x;
    int lane = tid & 63, w = tid >> 6;
    int lo = lane & 15, qd = lane >> 4;

    __shared__ __align__(16) float Sp[8][32][33];
    __shared__ __align__(16) __bf16 Pl[32][40];
    __shared__ float ml[32], ll[32], al[32];

    const u16* Qb = Q + (size_t)b * SEQ * DIM;
    const u16* Kb = Kmat + (size_t)b * SEQ * DIM;
    const u16* VTb = VT + (size_t)b * DIM * SEQ;

    bfx8 qf[2][4];
    #pragma unroll
    for (int i = 0; i < 2; i++)
        #pragma unroll
        for (int c = 0; c < 4; c++)
            qf[i][c] = *(const bfx8*)(Qb + (size_t)(q0 + i * 16 + lo) * DIM + w * 128 + c * 32 + qd * 8);

    fx4 oacc[2][8] = {};
    if (tid < 32) { ml[tid] = -INFINITY; ll[tid] = 0.0f; }
    __syncthreads();

    for (int kt = 0; kt <= qt; kt++) {
        int k0 = kt * 32;
        fx4 sp[2][2] = {};
        #pragma unroll
        for (int c = 0; c < 4; c++) {
            bfx8 kf[2];
            #pragma unroll
            for (int jn = 0; jn < 2; jn++)
                kf[jn] = *(const bfx8*)(Kb + (size_t)(k0 + jn * 16 + lo) * DIM + w * 128 + c * 32 + qd * 8);
            #pragma unroll
            for (int i = 0; i < 2; i++)
                #pragma unroll
                for (int jn = 0; jn < 2; jn++)
                    sp[i][jn] = __builtin_amdgcn_mfma_f32_16x16x32_bf16(qf[i][c], kf[jn], sp[i][jn], 0, 0, 0);
        }
        #pragma unroll
        for (int i = 0; i < 2; i++)
            #pragma unroll
            for (int jn = 0; jn < 2; jn++)
                #pragma unroll
                for (int r = 0; r < 4; r++)
                    Sp[w][i * 16 + qd * 4 + r][jn * 16 + lo] = sp[i][jn][r];
        __syncthreads();
        {
            int r = tid >> 4, ci = tid & 15;
            int q = q0 + r;
            float s0 = 0.0f, s1 = 0.0f;
            #pragma unroll
            for (int p = 0; p < 8; p++) { s0 += Sp[p][r][ci]; s1 += Sp[p][r][ci + 16]; }
            s0 = fminf(fmaxf(s0 * SCALE, -1e30f), 1e30f);
            s1 = fminf(fmaxf(s1 * SCALE, -1e30f), 1e30f);
            if (k0 + ci > q)      s0 = -INFINITY;
            if (k0 + ci + 16 > q) s1 = -INFINITY;
            float mx = fmaxf(s0, s1);
            #pragma unroll
            for (int off = 1; off < 16; off <<= 1) mx = fmaxf(mx, __shfl_xor(mx, off));
            float mo = ml[r];
            float mn = fmaxf(mo, mx);
            float p0 = __expf(s0 - mn), p1 = __expf(s1 - mn);
            Pl[r][ci] = (__bf16)p0;
            Pl[r][ci + 16] = (__bf16)p1;
            float ps = p0 + p1;
            #pragma unroll
            for (int off = 1; off < 16; off <<= 1) ps += __shfl_xor(ps, off);
            if (ci == 0) {
                float alpha = __expf(mo - mn);
                ll[r] = alpha * ll[r] + ps;
                ml[r] = mn;
                al[r] = alpha;
            }
        }
        __syncthreads();
        float alocal[2][4];
        #pragma unroll
        for (int i = 0; i < 2; i++)
            #pragma unroll
            for (int r = 0; r < 4; r++)
                alocal[i][r] = al[i * 16 + qd * 4 + r];
        #pragma unroll
        for (int i = 0; i < 2; i++)
            #pragma unroll
            for (int j = 0; j < 8; j++)
                #pragma unroll
                for (int r = 0; r < 4; r++)
                    oacc[i][j][r] *= alocal[i][r];
        bfx8 pf[2];
        #pragma unroll
        for (int i = 0; i < 2; i++)
            pf[i] = *(const bfx8*)(&Pl[i * 16 + lo][qd * 8]);
        #pragma unroll
        for (int j = 0; j < 8; j++) {
            bfx8 vf = *(const bfx8*)(VTb + (size_t)(w * 128 + j * 16 + lo) * SEQ + k0 + qd * 8);
            #pragma unroll
            for (int i = 0; i < 2; i++)
                oacc[i][j] = __builtin_amdgcn_mfma_f32_16x16x32_bf16(pf[i], vf, oacc[i][j], 0, 0, 0);
        }
    }

    float linv[2][4];
    #pragma unroll
    for (int i = 0; i < 2; i++)
        #pragma unroll
        for (int r = 0; r < 4; r++)
            linv[i][r] = 1.0f / ll[i * 16 + qd * 4 + r];
    float* Ob = O + (size_t)b * SEQ * DIM;
    #pragma unroll
    for (int i = 0; i < 2; i++)
        #pragma unroll
        for (int j = 0; j < 8; j++)
            #pragma unroll
            for (int r = 0; r < 4; r++) {
                int row = q0 + i * 16 + qd * 4 + r;
                int col = w * 128 + j * 16 + lo;
                Ob[(size_t)row * DIM + col] = oacc[i][j][r] * linv[i][r];
            }
}

// ---------------------------------------------------------------------------
extern "C" void kernel_launch(void* const* d_in, const int* in_sizes, int n_in,
                              void* d_out, int out_size, void* d_ws, size_t ws_size,
                              hipStream_t stream) {
    const float* x  = (const float*)d_in[0];
    const float* Wq = (const float*)d_in[1];
    const float* Wk = (const float*)d_in[2];
    const float* Wv = (const float*)d_in[3];

    u16* ws = (u16*)d_ws;
    u16* Qp  = ws;               // NEL bf16 (16 MiB)
    u16* Kp  = Qp + NEL;         // 16 MiB
    u16* VTp = Kp + NEL;         // 16 MiB
    // conversion staging (dead after gemm_fast) overlaps the P region
    u16* XBp = VTp + NEL;        // 16 MiB
    u16* WTp = XBp + NEL;        // 6 MiB
    // materialized P (all 4 batches) + Lrow
    u16*   Pm   = VTp + NEL;                                // 33.6 MiB
    float* Lrow = (float*)(Pm + (size_t)NBATCH * SEQ * SEQ);// 32 KiB

    size_t need_base = 3 * NEL * 2;                                   // 48 MiB
    size_t need_conv = NEL * 2 + (size_t)3 * 1024 * 1024 * 2;         // 22 MiB
    size_t need_mat  = (size_t)NBATCH * SEQ * SEQ * 2
                     + (size_t)NBATCH * SEQ * 4 + 1024;               // ~33.6 MiB
    bool fastg = ws_size >= need_base + need_conv;                    // 70 MiB
    bool mat   = ws_size >= need_base + need_mat;                     // ~82 MiB

    if (fastg && mat) {
        prep<<<dim3(11296), 256, 0, stream>>>(x, Wq, Wk, Wv, XBp, WTp, Lrow);
        gemm_fast<<<dim3(8, 64, 3), 256, 0, stream>>>(XBp, WTp, Qp, Kp, VTp);
        sgemm_exp<<<dim3(136, NBATCH), 512, 0, stream>>>(Qp, Kp, Pm, Lrow);
        pvgemm<<<dim3(128, NBATCH), 512, 0, stream>>>(Pm, VTp, Lrow, (float*)d_out);
    } else {
        gemm_legacy<<<dim3(8, 64, 3), 256, 0, stream>>>(x, Wq, Wk, Wv, Qp, Kp, VTp);
        flash_attn<<<dim3(SEQ / 32, NBATCH), 512, 0, stream>>>(
            Qp, Kp, VTp, (float*)d_out);
    }
}

// Round 13
// 246.930 us; speedup vs baseline: 2.1852x; 1.0331x over previous
//
#include <hip/hip_runtime.h>
#include <hip/hip_bf16.h>

typedef unsigned short u16;
typedef __bf16 bfx8 __attribute__((ext_vector_type(8)));
typedef float fx4 __attribute__((ext_vector_type(4)));

#define SEQ 2048
#define DIM 1024
#define NBATCH 4
#define SCALE 0.03125f  // 1/sqrt(1024)
#define NEL ((size_t)NBATCH * SEQ * DIM)   // 8388608 elems per Q/K/V

__device__ inline u16 f2bf(float f) {
    __bf16 h = (__bf16)f;
    return __builtin_bit_cast(unsigned short, h);
}

// async global->LDS, 16B per lane (dst must be wave-uniform base + lane*16;
// padding the LDS row stride is NOT possible -> xor-swizzle the SOURCE chunk)
#define GLL(gp, lp) __builtin_amdgcn_global_load_lds( \
    (const __attribute__((address_space(1))) unsigned int*)(gp), \
    (__attribute__((address_space(3))) unsigned int*)(lp), 16, 0, 0)

// ---------------------------------------------------------------------------
// prep: blocks [0,8192): convert x -> XB (bf16)
//       blocks [8192,10240): straight-convert Wq,Wk -> WBq,WBk (bf16, ORIGINAL
//         row-major layout, e contiguous — gemm_m contracts over e!)
//       blocks [10240,11264): transpose Wv -> WTv[e][d]
//       blocks [11264,11296): zero Lrow
// ---------------------------------------------------------------------------
__global__ __launch_bounds__(256) void prep(
    const float* __restrict__ X,
    const float* __restrict__ Wq, const float* __restrict__ Wk,
    const float* __restrict__ Wv,
    u16* __restrict__ XB, u16* __restrict__ WB, u16* __restrict__ WTv,
    float* __restrict__ Lrow)
{
    __shared__ u16 t[32][33];
    int bid = blockIdx.x;
    int tid = threadIdx.x;
    if (bid < 8192) {
        size_t i = (size_t)bid * 256 + tid;
        float4 v = ((const float4*)X)[i];
        uint2 pk;
        pk.x = (unsigned)f2bf(v.x) | ((unsigned)f2bf(v.y) << 16);
        pk.y = (unsigned)f2bf(v.z) | ((unsigned)f2bf(v.w) << 16);
        ((uint2*)XB)[i] = pk;
    } else if (bid < 10240) {
        int b2 = bid - 8192;                       // 0..2047
        const float* W = (b2 < 1024) ? Wq : Wk;
        u16* out = WB + (size_t)(b2 >> 10) * 1024 * 1024;
        size_t i = (size_t)(b2 & 1023) * 256 + tid;  // float4 units
        float4 v = ((const float4*)W)[i];
        uint2 pk;
        pk.x = (unsigned)f2bf(v.x) | ((unsigned)f2bf(v.y) << 16);
        pk.y = (unsigned)f2bf(v.z) | ((unsigned)f2bf(v.w) << 16);
        ((uint2*)out)[i] = pk;
    } else if (bid < 11264) {
        int t2 = bid - 10240;                      // 0..1023 tiles
        int n0 = (t2 & 31) * 32, k0 = (t2 >> 5) * 32;
        int tx = tid & 31, ty = tid >> 5;
        #pragma unroll
        for (int i = 0; i < 32; i += 8)
            t[ty + i][tx] = f2bf(Wv[(size_t)(k0 + ty + i) * 1024 + n0 + tx]);
        __syncthreads();
        #pragma unroll
        for (int i = 0; i < 32; i += 8)
            WTv[(size_t)(n0 + ty + i) * 1024 + k0 + tx] = t[tx][ty + i];
    } else {
        int i = (bid - 11264) * 256 + tid;   // 8192 floats
        Lrow[i] = 0.0f;
    }
}

// ---------------------------------------------------------------------------
// gemm_m: MT[d2][d1] = sum_e WBk[d2][e] * WBq[d1][e]  ( = M[d1][d2] where
// M = Wq Wk^T ).  Operands in ORIGINAL W layout (e contiguous).  BK=32,
// xor-swizzled GLL staging.  Grid (8,8).
// ---------------------------------------------------------------------------
__global__ __launch_bounds__(256) void gemm_m(
    const u16* __restrict__ WBk, const u16* __restrict__ WBq, u16* __restrict__ MT)
{
    int m0 = blockIdx.y * 128, n0 = blockIdx.x * 128;
    __shared__ __align__(16) u16 As[128 * 32];
    __shared__ __align__(16) u16 Bs[128 * 32];
    int tid = threadIdx.x, lane = tid & 63, w = tid >> 6;
    int wm = w >> 1, wn = w & 1, lo = lane & 15, qd = lane >> 4;
    fx4 acc[4][4] = {};

    int c0 = tid, c1 = tid + 256;
    const u16* a0 = WBk + (size_t)(m0 + (c0 >> 2)) * 1024 + (((c0 & 3) ^ ((c0 >> 2) & 3)) * 8);
    const u16* a1 = WBk + (size_t)(m0 + (c1 >> 2)) * 1024 + (((c1 & 3) ^ ((c1 >> 2) & 3)) * 8);
    const u16* b0 = WBq + (size_t)(n0 + (c0 >> 2)) * 1024 + (((c0 & 3) ^ ((c0 >> 2) & 3)) * 8);
    const u16* b1 = WBq + (size_t)(n0 + (c1 >> 2)) * 1024 + (((c1 & 3) ^ ((c1 >> 2) & 3)) * 8);

    int sw = (qd ^ (lo & 3)) * 8;
    for (int k0 = 0; k0 < 1024; k0 += 32) {
        GLL(a0 + k0, &As[(size_t)c0 * 8]);
        GLL(a1 + k0, &As[(size_t)c1 * 8]);
        GLL(b0 + k0, &Bs[(size_t)c0 * 8]);
        GLL(b1 + k0, &Bs[(size_t)c1 * 8]);
        __syncthreads();
        bfx8 af[4], bf[4];
        #pragma unroll
        for (int i = 0; i < 4; i++)
            af[i] = *(const bfx8*)(&As[(wm * 64 + i * 16 + lo) * 32 + sw]);
        #pragma unroll
        for (int j = 0; j < 4; j++)
            bf[j] = *(const bfx8*)(&Bs[(wn * 64 + j * 16 + lo) * 32 + sw]);
        #pragma unroll
        for (int i = 0; i < 4; i++)
            #pragma unroll
            for (int j = 0; j < 4; j++)
                acc[i][j] = __builtin_amdgcn_mfma_f32_16x16x32_bf16(af[i], bf[j], acc[i][j], 0, 0, 0);
        __syncthreads();
    }
    #pragma unroll
    for (int i = 0; i < 4; i++)
        #pragma unroll
        for (int j = 0; j < 4; j++)
            #pragma unroll
            for (int r = 0; r < 4; r++)
                MT[(size_t)(m0 + wm * 64 + i * 16 + qd * 4 + r) * 1024
                   + n0 + wn * 64 + j * 16 + lo] = f2bf(acc[i][j][r]);
}

// ---------------------------------------------------------------------------
// gemm_fast: z=0: Y = XB x MT^T (Y = X·M); z=1: V = XB x WTv^T stored
// TRANSPOSED as VT[b][d][s].  128x128 tile, BK=32, xor-swizzled GLL staging.
// NOTE: do NOT grow tile to 128x256 (r8: 2 WG/CU, 100us) and do NOT set
// min-waves>=4 on big acc (r9: scratch spill, 357us, 1.8GB traffic).
// ---------------------------------------------------------------------------
__global__ __launch_bounds__(256) void gemm_fast(
    const u16* __restrict__ XB, const u16* __restrict__ MT,
    const u16* __restrict__ WTv,
    u16* __restrict__ Yo, u16* __restrict__ VTo)
{
    const u16* Wz = (blockIdx.z == 0) ? MT : WTv;
    int m0 = blockIdx.y * 128, n0 = blockIdx.x * 128;

    __shared__ __align__(16) u16 As[128 * 32];
    __shared__ __align__(16) u16 Bs[128 * 32];
    __shared__ __align__(16) u16 Ct[64][132];

    int tid = threadIdx.x, lane = tid & 63, w = tid >> 6;
    int wm = w >> 1, wn = w & 1, lo = lane & 15, qd = lane >> 4;

    fx4 acc[4][4] = {};

    int c0 = tid, c1 = tid + 256;
    const u16* a0 = XB + (size_t)(m0 + (c0 >> 2)) * 1024 + (((c0 & 3) ^ ((c0 >> 2) & 3)) * 8);
    const u16* a1 = XB + (size_t)(m0 + (c1 >> 2)) * 1024 + (((c1 & 3) ^ ((c1 >> 2) & 3)) * 8);
    const u16* b0 = Wz + (size_t)(n0 + (c0 >> 2)) * 1024 + (((c0 & 3) ^ ((c0 >> 2) & 3)) * 8);
    const u16* b1 = Wz + (size_t)(n0 + (c1 >> 2)) * 1024 + (((c1 & 3) ^ ((c1 >> 2) & 3)) * 8);

    int sw = (qd ^ (lo & 3)) * 8;
    for (int k0 = 0; k0 < 1024; k0 += 32) {
        GLL(a0 + k0, &As[(size_t)c0 * 8]);
        GLL(a1 + k0, &As[(size_t)c1 * 8]);
        GLL(b0 + k0, &Bs[(size_t)c0 * 8]);
        GLL(b1 + k0, &Bs[(size_t)c1 * 8]);
        __syncthreads();

        bfx8 af[4], bf[4];
        #pragma unroll
        for (int i = 0; i < 4; i++)
            af[i] = *(const bfx8*)(&As[(wm * 64 + i * 16 + lo) * 32 + sw]);
        #pragma unroll
        for (int j = 0; j < 4; j++)
            bf[j] = *(const bfx8*)(&Bs[(wn * 64 + j * 16 + lo) * 32 + sw]);
        #pragma unroll
        for (int i = 0; i < 4; i++)
            #pragma unroll
            for (int j = 0; j < 4; j++)
                acc[i][j] = __builtin_amdgcn_mfma_f32_16x16x32_bf16(af[i], bf[j], acc[i][j], 0, 0, 0);
        __syncthreads();
    }

    if (blockIdx.z == 0) {
        #pragma unroll
        for (int i = 0; i < 4; i++)
            #pragma unroll
            for (int j = 0; j < 4; j++)
                #pragma unroll
                for (int r = 0; r < 4; r++) {
                    int row = m0 + wm * 64 + i * 16 + qd * 4 + r;
                    int col = n0 + wn * 64 + j * 16 + lo;
                    Yo[(size_t)row * 1024 + col] = f2bf(acc[i][j][r]);
                }
    } else {
        #pragma unroll
        for (int half = 0; half < 2; half++) {
            __syncthreads();
            if (wm == half) {
                #pragma unroll
                for (int i = 0; i < 4; i++)
                    #pragma unroll
                    for (int j = 0; j < 4; j++)
                        #pragma unroll
                        for (int r = 0; r < 4; r++)
                            Ct[i * 16 + qd * 4 + r][wn * 64 + j * 16 + lo] = f2bf(acc[i][j][r]);
            }
            __syncthreads();
            #pragma unroll
            for (int e = tid; e < 64 * 128; e += 256) {
                int d = e >> 6, sl = e & 63;
                int gr = m0 + half * 64 + sl;
                int bb = gr >> 11, s = gr & 2047;
                VTo[((size_t)bb * DIM + (n0 + d)) * SEQ + s] = Ct[sl][d];
            }
        }
    }
}

// ---------------------------------------------------------------------------
// sgemm_exp: P = exp(scale*(Y x XB^T) masked), causal 128x128 tiles, bf16,
// UNNORMALIZED (no max-subtraction; clamped +-30).  Row sums -> atomicAdd.
// 512 thr / 8 waves (2m x 4n), BK=64, xor-swizzled staging.
// ---------------------------------------------------------------------------
__global__ __launch_bounds__(512) void sgemm_exp(
    const u16* __restrict__ Y, const u16* __restrict__ XB,
    u16* __restrict__ P, float* __restrict__ Lrow)
{
    int b = blockIdx.y;
    int t = blockIdx.x;                  // 0..135 triangular tile
    int i = (int)((sqrtf(8.0f * t + 1.0f) - 1.0f) * 0.5f);
    while ((i + 1) * (i + 2) / 2 <= t) i++;
    while (i * (i + 1) / 2 > t) i--;
    int j = t - i * (i + 1) / 2;

    const u16* Yb = Y + (size_t)b * SEQ * DIM;
    const u16* Xb = XB + (size_t)b * SEQ * DIM;
    u16* Pb = P + (size_t)b * SEQ * SEQ;
    float* Lb = Lrow + (size_t)b * SEQ;

    int m0 = i * 128, n0 = j * 128;

    __shared__ __align__(16) u16 As[128 * 64];
    __shared__ __align__(16) u16 Bs[128 * 64];

    int tid = threadIdx.x, lane = tid & 63, w = tid >> 6;
    int wm = w >> 2, wn = w & 3, lo = lane & 15, qd = lane >> 4;

    fx4 acc[4][2] = {};

    int c0 = tid, c1 = tid + 512;        // 1024 chunks of 16B per operand
    const u16* a0 = Yb + (size_t)(m0 + (c0 >> 3)) * 1024 + (((c0 & 7) ^ ((c0 >> 3) & 7)) * 8);
    const u16* a1 = Yb + (size_t)(m0 + (c1 >> 3)) * 1024 + (((c1 & 7) ^ ((c1 >> 3) & 7)) * 8);
    const u16* b0 = Xb + (size_t)(n0 + (c0 >> 3)) * 1024 + (((c0 & 7) ^ ((c0 >> 3) & 7)) * 8);
    const u16* b1 = Xb + (size_t)(n0 + (c1 >> 3)) * 1024 + (((c1 & 7) ^ ((c1 >> 3) & 7)) * 8);

    for (int k0 = 0; k0 < 1024; k0 += 64) {
        GLL(a0 + k0, &As[(size_t)c0 * 8]);
        GLL(a1 + k0, &As[(size_t)c1 * 8]);
        GLL(b0 + k0, &Bs[(size_t)c0 * 8]);
        GLL(b1 + k0, &Bs[(size_t)c1 * 8]);
        __syncthreads();

        #pragma unroll
        for (int kc = 0; kc < 2; kc++) {
            int sw = ((kc * 4 + qd) ^ (lo & 7)) * 8;
            bfx8 af[4], bf[2];
            #pragma unroll
            for (int ii = 0; ii < 4; ii++)
                af[ii] = *(const bfx8*)(&As[(wm * 64 + ii * 16 + lo) * 64 + sw]);
            #pragma unroll
            for (int jn = 0; jn < 2; jn++)
                bf[jn] = *(const bfx8*)(&Bs[(wn * 32 + jn * 16 + lo) * 64 + sw]);
            #pragma unroll
            for (int ii = 0; ii < 4; ii++)
                #pragma unroll
                for (int jn = 0; jn < 2; jn++)
                    acc[ii][jn] = __builtin_amdgcn_mfma_f32_16x16x32_bf16(af[ii], bf[jn], acc[ii][jn], 0, 0, 0);
        }
        __syncthreads();
    }

    #pragma unroll
    for (int ii = 0; ii < 4; ii++)
        #pragma unroll
        for (int r = 0; r < 4; r++) {
            int row = m0 + wm * 64 + ii * 16 + qd * 4 + r;
            float rs = 0.0f;
            #pragma unroll
            for (int jn = 0; jn < 2; jn++) {
                int col = n0 + wn * 32 + jn * 16 + lo;
                float s = acc[ii][jn][r] * SCALE;
                s = fminf(fmaxf(s, -30.0f), 30.0f);
                float p = (col > row) ? 0.0f : __expf(s);
                Pb[(size_t)row * SEQ + col] = f2bf(p);
                rs += p;
            }
            #pragma unroll
            for (int off = 1; off < 16; off <<= 1) rs += __shfl_xor(rs, off);
            if (lo == 0) atomicAdd(&Lb[row], rs);
        }
}

// ---------------------------------------------------------------------------
// pvgemm: O[q][d] = P[q][k] x VT[d][k] / L[q].  Triangular k-extent, big
// q-blocks first.  512 thr / 8 waves (2m x 4n), BK=64, xor-swizzled staging.
// ---------------------------------------------------------------------------
__global__ __launch_bounds__(512) void pvgemm(
    const u16* __restrict__ P, const u16* __restrict__ VT,
    const float* __restrict__ Lrow, float* __restrict__ O)
{
    int b = blockIdx.y;
    int qb = 15 - (int)(blockIdx.x >> 3);   // big k-extent first
    int db = blockIdx.x & 7;
    int m0 = qb * 128, n0 = db * 128;
    int kext = (qb + 1) * 128;

    const u16* Pb = P + (size_t)b * SEQ * SEQ;
    const u16* Vb = VT + (size_t)b * DIM * SEQ;
    const float* Lb = Lrow + (size_t)b * SEQ;
    float* Ob = O + (size_t)b * SEQ * DIM;

    __shared__ __align__(16) u16 As[128 * 64];
    __shared__ __align__(16) u16 Bs[128 * 64];

    int tid = threadIdx.x, lane = tid & 63, w = tid >> 6;
    int wm = w >> 2, wn = w & 3, lo = lane & 15, qd = lane >> 4;

    fx4 acc[4][2] = {};

    int c0 = tid, c1 = tid + 512;
    const u16* a0 = Pb + (size_t)(m0 + (c0 >> 3)) * SEQ + (((c0 & 7) ^ ((c0 >> 3) & 7)) * 8);
    const u16* a1 = Pb + (size_t)(m0 + (c1 >> 3)) * SEQ + (((c1 & 7) ^ ((c1 >> 3) & 7)) * 8);
    const u16* b0 = Vb + (size_t)(n0 + (c0 >> 3)) * SEQ + (((c0 & 7) ^ ((c0 >> 3) & 7)) * 8);
    const u16* b1 = Vb + (size_t)(n0 + (c1 >> 3)) * SEQ + (((c1 & 7) ^ ((c1 >> 3) & 7)) * 8);

    for (int k0 = 0; k0 < kext; k0 += 64) {
        GLL(a0 + k0, &As[(size_t)c0 * 8]);
        GLL(a1 + k0, &As[(size_t)c1 * 8]);
        GLL(b0 + k0, &Bs[(size_t)c0 * 8]);
        GLL(b1 + k0, &Bs[(size_t)c1 * 8]);
        __syncthreads();

        #pragma unroll
        for (int kc = 0; kc < 2; kc++) {
            int sw = ((kc * 4 + qd) ^ (lo & 7)) * 8;
            bfx8 af[4], bf[2];
            #pragma unroll
            for (int ii = 0; ii < 4; ii++)
                af[ii] = *(const bfx8*)(&As[(wm * 64 + ii * 16 + lo) * 64 + sw]);
            #pragma unroll
            for (int jn = 0; jn < 2; jn++)
                bf[jn] = *(const bfx8*)(&Bs[(wn * 32 + jn * 16 + lo) * 64 + sw]);
            #pragma unroll
            for (int ii = 0; ii < 4; ii++)
                #pragma unroll
                for (int jn = 0; jn < 2; jn++)
                    acc[ii][jn] = __builtin_amdgcn_mfma_f32_16x16x32_bf16(af[ii], bf[jn], acc[ii][jn], 0, 0, 0);
        }
        __syncthreads();
    }

    #pragma unroll
    for (int ii = 0; ii < 4; ii++)
        #pragma unroll
        for (int r = 0; r < 4; r++) {
            int row = m0 + wm * 64 + ii * 16 + qd * 4 + r;
            float linv = 1.0f / Lb[row];
            #pragma unroll
            for (int jn = 0; jn < 2; jn++) {
                int col = n0 + wn * 32 + jn * 16 + lo;
                Ob[(size_t)row * DIM + col] = acc[ii][jn][r] * linv;
            }
        }
}

// ---------------------------------------------------------------------------
// Fallback path (small ws): gemm_legacy + flash_attn, unchanged.
// ---------------------------------------------------------------------------
__global__ __launch_bounds__(256) void gemm_legacy(
    const float* __restrict__ X,
    const float* __restrict__ Wq, const float* __restrict__ Wk, const float* __restrict__ Wv,
    u16* __restrict__ Qo, u16* __restrict__ Ko, u16* __restrict__ VTo)
{
    const int K = 1024, N = 1024;
    const float* W = (blockIdx.z == 0) ? Wq : (blockIdx.z == 1) ? Wk : Wv;
    int m0 = blockIdx.y * 128, n0 = blockIdx.x * 128;
    __shared__ __align__(16) u16 As[128 * 40];
    __shared__ __align__(16) u16 Bs[128 * 40];
    __shared__ __align__(16) u16 Ct[64][132];
    int tid = threadIdx.x, lane = tid & 63, w = tid >> 6;
    int wm = w >> 1, wn = w & 1, lo = lane & 15, qd = lane >> 4;
    fx4 acc[4][4] = {};
    for (int k0 = 0; k0 < K; k0 += 32) {
        #pragma unroll
        for (int c = tid; c < 1024; c += 256) {
            int row = c >> 3, cc = (c & 7) * 4;
            float4 v = *(const float4*)(X + (size_t)(m0 + row) * K + k0 + cc);
            uint2 pk;
            pk.x = (unsigned)f2bf(v.x) | ((unsigned)f2bf(v.y) << 16);
            pk.y = (unsigned)f2bf(v.z) | ((unsigned)f2bf(v.w) << 16);
            *(uint2*)(&As[row * 40 + cc]) = pk;
        }
        #pragma unroll
        for (int c = tid; c < 1024; c += 256) {
            int r = c >> 5, cc = (c & 31) * 4;
            float4 v = *(const float4*)(W + (size_t)(k0 + r) * N + n0 + cc);
            Bs[(cc + 0) * 40 + r] = f2bf(v.x);
            Bs[(cc + 1) * 40 + r] = f2bf(v.y);
            Bs[(cc + 2) * 40 + r] = f2bf(v.z);
            Bs[(cc + 3) * 40 + r] = f2bf(v.w);
        }
        __syncthreads();
        bfx8 af[4], bf[4];
        #pragma unroll
        for (int i = 0; i < 4; i++)
            af[i] = *(const bfx8*)(&As[(wm * 64 + i * 16 + lo) * 40 + qd * 8]);
        #pragma unroll
        for (int j = 0; j < 4; j++)
            bf[j] = *(const bfx8*)(&Bs[(wn * 64 + j * 16 + lo) * 40 + qd * 8]);
        #pragma unroll
        for (int i = 0; i < 4; i++)
            #pragma unroll
            for (int j = 0; j < 4; j++)
                acc[i][j] = __builtin_amdgcn_mfma_f32_16x16x32_bf16(af[i], bf[j], acc[i][j], 0, 0, 0);
        __syncthreads();
    }
    if (blockIdx.z != 2) {
        u16* C = (blockIdx.z == 0) ? Qo : Ko;
        #pragma unroll
        for (int i = 0; i < 4; i++)
            #pragma unroll
            for (int j = 0; j < 4; j++)
                #pragma unroll
                for (int r = 0; r < 4; r++) {
                    int row = m0 + wm * 64 + i * 16 + qd * 4 + r;
                    int col = n0 + wn * 64 + j * 16 + lo;
                    C[(size_t)row * N + col] = f2bf(acc[i][j][r]);
                }
    } else {
        #pragma unroll
        for (int half = 0; half < 2; half++) {
            __syncthreads();
            if (wm == half) {
                #pragma unroll
                for (int i = 0; i < 4; i++)
                    #pragma unroll
                    for (int j = 0; j < 4; j++)
                        #pragma unroll
                        for (int r = 0; r < 4; r++)
                            Ct[i * 16 + qd * 4 + r][wn * 64 + j * 16 + lo] = f2bf(acc[i][j][r]);
            }
            __syncthreads();
            #pragma unroll
            for (int e = tid; e < 64 * 128; e += 256) {
                int d = e >> 6, sl = e & 63;
                int gr = m0 + half * 64 + sl;
                int bb = gr >> 11, s = gr & 2047;
                VTo[((size_t)bb * DIM + (n0 + d)) * SEQ + s] = Ct[sl][d];
            }
        }
    }
}

__global__ __launch_bounds__(512) void flash_attn(
    const u16* __restrict__ Q, const u16* __restrict__ Kmat,
    const u16* __restrict__ VT, float* __restrict__ O)
{
    int b = blockIdx.y;
    int qt = (int)(gridDim.x - 1) - (int)blockIdx.x;
    int q0 = qt * 32;
    int tid = threadIdx.x;
    int lane = tid & 63, w = tid >> 6;
    int lo = lane & 15, qd = lane >> 4;

    __shared__ __align__(16) float Sp[8][32][33];
    __shared__ __align__(16) __bf16 Pl[32][40];
    __shared__ float ml[32], ll[32], al[32];

    const u16* Qb = Q + (size_t)b * SEQ * DIM;
    const u16* Kb = Kmat + (size_t)b * SEQ * DIM;
    const u16* VTb = VT + (size_t)b * DIM * SEQ;

    bfx8 qf[2][4];
    #pragma unroll
    for (int i = 0; i < 2; i++)
        #pragma unroll
        for (int c = 0; c < 4; c++)
            qf[i][c] = *(const bfx8*)(Qb + (size_t)(q0 + i * 16 + lo) * DIM + w * 128 + c * 32 + qd * 8);

    fx4 oacc[2][8] = {};
    if (tid < 32) { ml[tid] = -INFINITY; ll[tid] = 0.0f; }
    __syncthreads();

    for (int kt = 0; kt <= qt; kt++) {
        int k0 = kt * 32;
        fx4 sp[2][2] = {};
        #pragma unroll
        for (int c = 0; c < 4; c++) {
            bfx8 kf[2];
            #pragma unroll
            for (int jn = 0; jn < 2; jn++)
                kf[jn] = *(const bfx8*)(Kb + (size_t)(k0 + jn * 16 + lo) * DIM + w * 128 + c * 32 + qd * 8);
            #pragma unroll
            for (int i = 0; i < 2; i++)
                #pragma unroll
                for (int jn = 0; jn < 2; jn++)
                    sp[i][jn] = __builtin_amdgcn_mfma_f32_16x16x32_bf16(qf[i][c], kf[jn], sp[i][jn], 0, 0, 0);
        }
        #pragma unroll
        for (int i = 0; i < 2; i++)
            #pragma unroll
            for (int jn = 0; jn < 2; jn++)
                #pragma unroll
                for (int r = 0; r < 4; r++)
                    Sp[w][i * 16 + qd * 4 + r][jn * 16 + lo] = sp[i][jn][r];
        __syncthreads();
        {
            int r = tid >> 4, ci = tid & 15;
            int q = q0 + r;
            float s0 = 0.0f, s1 = 0.0f;
            #pragma unroll
            for (int p = 0; p < 8; p++) { s0 += Sp[p][r][ci]; s1 += Sp[p][r][ci + 16]; }
            s0 = fminf(fmaxf(s0 * SCALE, -1e30f), 1e30f);
            s1 = fminf(fmaxf(s1 * SCALE, -1e30f), 1e30f);
            if (k0 + ci > q)      s0 = -INFINITY;
            if (k0 + ci + 16 > q) s1 = -INFINITY;
            float mx = fmaxf(s0, s1);
            #pragma unroll
            for (int off = 1; off < 16; off <<= 1) mx = fmaxf(mx, __shfl_xor(mx, off));
            float mo = ml[r];
            float mn = fmaxf(mo, mx);
            float p0 = __expf(s0 - mn), p1 = __expf(s1 - mn);
            Pl[r][ci] = (__bf16)p0;
            Pl[r][ci + 16] = (__bf16)p1;
            float ps = p0 + p1;
            #pragma unroll
            for (int off = 1; off < 16; off <<= 1) ps += __shfl_xor(ps, off);
            if (ci == 0) {
                float alpha = __expf(mo - mn);
                ll[r] = alpha * ll[r] + ps;
                ml[r] = mn;
                al[r] = alpha;
            }
        }
        __syncthreads();
        float alocal[2][4];
        #pragma unroll
        for (int i = 0; i < 2; i++)
            #pragma unroll
            for (int r = 0; r < 4; r++)
                alocal[i][r] = al[i * 16 + qd * 4 + r];
        #pragma unroll
        for (int i = 0; i < 2; i++)
            #pragma unroll
            for (int j = 0; j < 8; j++)
                #pragma unroll
                for (int r = 0; r < 4; r++)
                    oacc[i][j][r] *= alocal[i][r];
        bfx8 pf[2];
        #pragma unroll
        for (int i = 0; i < 2; i++)
            pf[i] = *(const bfx8*)(&Pl[i * 16 + lo][qd * 8]);
        #pragma unroll
        for (int j = 0; j < 8; j++) {
            bfx8 vf = *(const bfx8*)(VTb + (size_t)(w * 128 + j * 16 + lo) * SEQ + k0 + qd * 8);
            #pragma unroll
            for (int i = 0; i < 2; i++)
                oacc[i][j] = __builtin_amdgcn_mfma_f32_16x16x32_bf16(pf[i], vf, oacc[i][j], 0, 0, 0);
        }
    }

    float linv[2][4];
    #pragma unroll
    for (int i = 0; i < 2; i++)
        #pragma unroll
        for (int r = 0; r < 4; r++)
            linv[i][r] = 1.0f / ll[i * 16 + qd * 4 + r];
    float* Ob = O + (size_t)b * SEQ * DIM;
    #pragma unroll
    for (int i = 0; i < 2; i++)
        #pragma unroll
        for (int j = 0; j < 8; j++)
            #pragma unroll
            for (int r = 0; r < 4; r++) {
                int row = q0 + i * 16 + qd * 4 + r;
                int col = w * 128 + j * 16 + lo;
                Ob[(size_t)row * DIM + col] = oacc[i][j][r] * linv[i][r];
            }
}

// ---------------------------------------------------------------------------
extern "C" void kernel_launch(void* const* d_in, const int* in_sizes, int n_in,
                              void* d_out, int out_size, void* d_ws, size_t ws_size,
                              hipStream_t stream) {
    const float* x  = (const float*)d_in[0];
    const float* Wq = (const float*)d_in[1];
    const float* Wk = (const float*)d_in[2];
    const float* Wv = (const float*)d_in[3];

    u16* ws = (u16*)d_ws;
    // mat-path layout: Y, VT, XB, WB(q,k straight), WTv, MT, P, Lrow
    u16* Yp  = ws;                                   // NEL (16 MiB)
    u16* VTp = ws + NEL;                             // NEL
    u16* XBp = ws + 2 * NEL;                         // NEL
    u16* WBp = ws + 3 * NEL;                         // 2 MiElem (4 MiB)
    u16* WTv = WBp + (size_t)2 * 1024 * 1024;        // 1 MiElem (2 MiB)
    u16* MTp = WTv + (size_t)1024 * 1024;            // 1 MiElem (2 MiB)
    u16* Pm  = MTp + (size_t)1024 * 1024;            // 4*SEQ*SEQ (33.6 MiB)
    float* Lrow = (float*)(Pm + (size_t)NBATCH * SEQ * SEQ);

    size_t need_mat = ((size_t)3 * NEL + (size_t)4 * 1024 * 1024
                     + (size_t)NBATCH * SEQ * SEQ) * 2
                     + (size_t)NBATCH * SEQ * 4 + 1024;   // ~92.3 MiB

    if (ws_size >= need_mat) {
        prep<<<dim3(11296), 256, 0, stream>>>(x, Wq, Wk, Wv, XBp, WBp, WTv, Lrow);
        gemm_m<<<dim3(8, 8), 256, 0, stream>>>(
            WBp + (size_t)1024 * 1024 /*WBk*/, WBp /*WBq*/, MTp);
        gemm_fast<<<dim3(8, 64, 2), 256, 0, stream>>>(XBp, MTp, WTv, Yp, VTp);
        sgemm_exp<<<dim3(136, NBATCH), 512, 0, stream>>>(Yp, XBp, Pm, Lrow);
        pvgemm<<<dim3(128, NBATCH), 512, 0, stream>>>(Pm, VTp, Lrow, (float*)d_out);
    } else {
        u16* Qp = ws; u16* Kp = ws + NEL; u16* VTf = ws + 2 * NEL;
        gemm_legacy<<<dim3(8, 64, 3), 256, 0, stream>>>(x, Wq, Wk, Wv, Qp, Kp, VTf);
        flash_attn<<<dim3(SEQ / 32, NBATCH), 512, 0, stream>>>(
            Qp, Kp, VTf, (float*)d_out);
    }
}